// Round 1
// baseline (2702.895 us; speedup 1.0000x reference)
//
#include <hip/hip_runtime.h>
#include <cstdint>

// ---- problem constants ----
#define B_   256
#define NPOS 196        // 14*14
#define D_   2048
#define H_   1024
#define A_   512
#define SI_  1024
#define WI_  1024
#define ST_  256
#define T_   10

#define N1 4864   // [dec_att_w(512); w_hh(4096); stop_p_w(256)]  K=1024
#define N2 5120   // [w_ih(4096); topic_c_w(1024)]                K=1024
#define N3 1280   // [topic_h_w(1024); stop_c_w(256)]             K=1024

typedef __attribute__((ext_vector_type(8))) short bf16x8;
typedef __attribute__((ext_vector_type(4))) float f32x4;

__device__ __forceinline__ float b2f(short s) {
  union { unsigned int u; float f; } c;
  c.u = ((unsigned int)(unsigned short)s) << 16;
  return c.f;
}
__device__ __forceinline__ short f2b(float f) {
  union { float f; unsigned int u; } c; c.f = f;
  unsigned int u = c.u + 0x7fffu + ((c.u >> 16) & 1u);  // RNE
  return (short)(u >> 16);
}
__device__ __forceinline__ float sigm(float x) { return 1.f / (1.f + expf(-x)); }

#define GLDS16(g, l) __builtin_amdgcn_global_load_lds( \
    (const __attribute__((address_space(1))) void*)(g), \
    (__attribute__((address_space(3))) void*)(l), 16, 0, 0)

// ---------------- fp32 -> bf16 convert ----------------
__global__ void cvt_k(const float* __restrict__ in, short* __restrict__ out, long n)
{
  long i = ((long)blockIdx.x * blockDim.x + threadIdx.x) * 8;
  long stride = (long)gridDim.x * blockDim.x * 8;
  for (; i < n; i += stride) {
    float4 a = *(const float4*)(in + i);
    float4 b = *(const float4*)(in + i + 4);
    bf16x8 o;
    o[0]=f2b(a.x); o[1]=f2b(a.y); o[2]=f2b(a.z); o[3]=f2b(a.w);
    o[4]=f2b(b.x); o[5]=f2b(b.y); o[6]=f2b(b.z); o[7]=f2b(b.w);
    *(bf16x8*)(out + i) = o;
  }
}

// ---------------- bf16 MFMA GEMM: C[M,N] = A[M,K] * B[N,K]^T + bias[N] ----------------
// m97 structure: 128x128 tile, BK=64, 4 waves (2x2), global_load_lds width 16.
// M,N multiples of 128; K multiple of 64.
template<int OUTBF16>
__global__ __launch_bounds__(256) void gemm_bt_k(
    const short* __restrict__ Aptr, const short* __restrict__ Bptr,
    const float* __restrict__ bias, void* __restrict__ Cout,
    int M, int N, int K)
{
  __shared__ short As[128*64];
  __shared__ short Bs[128*64];
  const int tid = threadIdx.x;
  const int l = tid & 63, wv = tid >> 6;
  const int wr = wv >> 1, wc = wv & 1;
  const size_t m0 = (size_t)blockIdx.x * 128;
  const size_t n0 = (size_t)blockIdx.y * 128;
  const int srow = l >> 3, scol = (l & 7) * 8;   // staging coords within 1KB chunk
  const int lr = l & 15, lg = l >> 4;            // fragment coords

  f32x4 acc[4][4];
  #pragma unroll
  for (int i = 0; i < 4; ++i)
    #pragma unroll
    for (int j = 0; j < 4; ++j) acc[i][j] = (f32x4){0.f, 0.f, 0.f, 0.f};

  for (int k0 = 0; k0 < K; k0 += 64) {
    #pragma unroll
    for (int i = 0; i < 4; ++i) {
      const int ch  = i * 4 + wv;        // 16 chunks of 1KB per 16KB tile
      const int row = ch * 8 + srow;     // tile row (8 rows / chunk, 128B rows)
      GLDS16(Aptr + (m0 + row) * (size_t)K + k0 + scol, As + ch * 512);
      GLDS16(Bptr + (n0 + row) * (size_t)K + k0 + scol, Bs + ch * 512);
    }
    __syncthreads();   // drains vmcnt (compiler-inserted) + barrier
    #pragma unroll
    for (int kk = 0; kk < 64; kk += 32) {
      bf16x8 af[4], bfr[4];
      #pragma unroll
      for (int m = 0; m < 4; ++m)
        af[m] = *(const bf16x8*)(As + (wr*64 + m*16 + lr)*64 + kk + lg*8);
      #pragma unroll
      for (int n = 0; n < 4; ++n)
        bfr[n] = *(const bf16x8*)(Bs + (wc*64 + n*16 + lr)*64 + kk + lg*8);
      #pragma unroll
      for (int m = 0; m < 4; ++m)
        #pragma unroll
        for (int n = 0; n < 4; ++n)
          acc[m][n] = __builtin_amdgcn_mfma_f32_16x16x32_bf16(af[m], bfr[n], acc[m][n], 0, 0, 0);
    }
    __syncthreads();
  }

  // epilogue: C/D layout col=lane&15, row=(lane>>4)*4+reg  (m89-verified)
  #pragma unroll
  for (int m = 0; m < 4; ++m) {
    const size_t row = m0 + wr*64 + m*16 + lg*4;
    #pragma unroll
    for (int n = 0; n < 4; ++n) {
      const size_t col = n0 + wc*64 + n*16 + lr;
      const float bv = bias[col];
      #pragma unroll
      for (int r = 0; r < 4; ++r) {
        const float v = acc[m][n][r] + bv;
        if (OUTBF16) ((short*)Cout)[(row + r) * (size_t)N + col] = f2b(v);
        else         ((float*)Cout)[(row + r) * (size_t)N + col] = v;
      }
    }
  }
}

// ---------------- attention: logits -> softmax -> att_out, one block per batch ----------------
template<int V16>
__global__ __launch_bounds__(256) void att_k(
    const void* __restrict__ vptr,       // bf16 ws (V16) or fp32 input
    const short* __restrict__ encp,      // [B, 196, 512] bf16
    const float* __restrict__ g1,        // dec = cols [0,512) of [B, N1] f32
    const float* __restrict__ fullw,     // [512] f32
    short* __restrict__ attout)          // [B, 2048] bf16
{
  const int b = blockIdx.x;
  const int tid = threadIdx.x;
  const int l = tid & 63, wv = tid >> 6;
  __shared__ float dec_s[A_];
  __shared__ float fw_s[A_];
  __shared__ float sc[NPOS];
  __shared__ float red[8];

  for (int i = tid; i < A_; i += 256) {
    dec_s[i] = g1[(size_t)b * N1 + i];
    fw_s[i]  = fullw[i];
  }
  __syncthreads();

  // logits[n] = sum_a tanh(encp[n,a] + dec[a]) * fw[a]; wave w handles n = w,w+4,...
  const short* ep = encp + (size_t)b * NPOS * A_;
  for (int n = wv; n < NPOS; n += 4) {
    bf16x8 e = *(const bf16x8*)(ep + (size_t)n * A_ + l * 8);
    float s = 0.f;
    #pragma unroll
    for (int j = 0; j < 8; ++j)
      s += tanhf(b2f(e[j]) + dec_s[l*8 + j]) * fw_s[l*8 + j];
    #pragma unroll
    for (int o = 32; o; o >>= 1) s += __shfl_down(s, o);
    if (l == 0) sc[n] = s;
  }
  __syncthreads();

  // softmax over 196
  float lm = (tid < NPOS) ? sc[tid] : -3e38f;
  #pragma unroll
  for (int o = 32; o; o >>= 1) lm = fmaxf(lm, __shfl_down(lm, o));
  if (l == 0) red[wv] = lm;
  __syncthreads();
  const float mx = fmaxf(fmaxf(red[0], red[1]), fmaxf(red[2], red[3]));
  const float ev = (tid < NPOS) ? expf(sc[tid] - mx) : 0.f;
  float es = ev;
  #pragma unroll
  for (int o = 32; o; o >>= 1) es += __shfl_down(es, o);
  if (l == 0) red[4 + wv] = es;
  __syncthreads();
  const float inv = 1.f / (red[4] + red[5] + red[6] + red[7]);
  if (tid < NPOS) sc[tid] = ev * inv;
  __syncthreads();

  // att_out[d] = sum_n sc[n] * v[b,n,d]; thread owns d = tid*8..tid*8+7
  float acc[8] = {0,0,0,0,0,0,0,0};
  const int d0 = tid * 8;
  if (V16) {
    const short* vb = (const short*)vptr + (size_t)b * NPOS * D_;
    #pragma unroll 4
    for (int n = 0; n < NPOS; ++n) {
      const float s = sc[n];
      bf16x8 vvv = *(const bf16x8*)(vb + (size_t)n * D_ + d0);
      #pragma unroll
      for (int j = 0; j < 8; ++j) acc[j] += s * b2f(vvv[j]);
    }
  } else {
    const float* vf = (const float*)vptr + (size_t)b * NPOS * D_;
    #pragma unroll 2
    for (int n = 0; n < NPOS; ++n) {
      const float s = sc[n];
      float4 v0 = *(const float4*)(vf + (size_t)n * D_ + d0);
      float4 v1 = *(const float4*)(vf + (size_t)n * D_ + d0 + 4);
      acc[0] += s*v0.x; acc[1] += s*v0.y; acc[2] += s*v0.z; acc[3] += s*v0.w;
      acc[4] += s*v1.x; acc[5] += s*v1.y; acc[6] += s*v1.z; acc[7] += s*v1.w;
    }
  }
  bf16x8 o8;
  #pragma unroll
  for (int j = 0; j < 8; ++j) o8[j] = f2b(acc[j]);
  *(bf16x8*)(attout + (size_t)b * D_ + d0) = o8;
}

// ---------------- LSTM cell: gates = g3[:, :4096] + g1[:, 512:4608] ----------------
__global__ __launch_bounds__(256) void lstm_k(
    const float* __restrict__ g1, const float* __restrict__ g3,
    float* __restrict__ c, short* __restrict__ hbf)
{
  const int idx = blockIdx.x * 256 + threadIdx.x;   // 0 .. B*H-1
  const int b = idx >> 10, j = idx & 1023;
  const float* gi = g3 + (size_t)b * N2;
  const float* gh = g1 + (size_t)b * N1 + 512;
  const float iv = gi[j]        + gh[j];
  const float fv = gi[1024 + j] + gh[1024 + j];
  const float gv = gi[2048 + j] + gh[2048 + j];
  const float ov = gi[3072 + j] + gh[3072 + j];
  const float cn = sigm(fv) * c[idx] + sigm(iv) * tanhf(gv);
  const float hn = sigm(ov) * tanhf(cn);
  c[idx] = cn;
  hbf[idx] = f2b(hn);
}

// ---------------- epilogue: topic + stop-path p ----------------
__global__ __launch_bounds__(256) void final_k(
    const float* __restrict__ g1, const float* __restrict__ g3,
    const float* __restrict__ g5, const float* __restrict__ fw,
    const float* __restrict__ fb, float* __restrict__ out_t,
    float* __restrict__ out_p, int t)
{
  const int b = blockIdx.x, tid = threadIdx.x;
  const float* t5 = g5 + (size_t)b * N3;
  const float* t3 = g3 + (size_t)b * N2 + 4096;
  float* ot = out_t + (size_t)b * (T_ * WI_) + (size_t)t * WI_;
  for (int j = tid; j < WI_; j += 256)
    ot[j] = tanhf(t5[j] + t3[j]);
  __shared__ float pp[ST_];
  pp[tid] = tanhf(g1[(size_t)b * N1 + 4608 + tid] + t5[1024 + tid]);
  __syncthreads();
  const int wv = tid >> 6, l = tid & 63;
  if (wv < 2) {
    float s = 0.f;
    #pragma unroll
    for (int k = 0; k < 4; ++k) s += pp[l + 64*k] * fw[wv*ST_ + l + 64*k];
    #pragma unroll
    for (int o = 32; o; o >>= 1) s += __shfl_down(s, o);
    if (l == 0) out_p[(size_t)b * (T_*2) + t*2 + wv] = s + fb[wv];
  }
}

// ---------------- host ----------------
extern "C" void kernel_launch(void* const* d_in, const int* in_sizes, int n_in,
                              void* d_out, int out_size, void* d_ws, size_t ws_size,
                              hipStream_t stream)
{
  const float* vis       = (const float*)d_in[0];
  // d_in[1] captions: only determines T (=10), unused
  const float* enc_att_w = (const float*)d_in[2];
  const float* enc_att_b = (const float*)d_in[3];
  const float* dec_att_w = (const float*)d_in[4];
  const float* dec_att_b = (const float*)d_in[5];
  const float* full_att_w= (const float*)d_in[6];
  // d_in[7] full_att_b: softmax shift-invariant, unused
  const float* ctx_w     = (const float*)d_in[8];
  const float* ctx_b     = (const float*)d_in[9];
  const float* w_ih      = (const float*)d_in[10];
  const float* b_ih      = (const float*)d_in[11];
  const float* w_hh      = (const float*)d_in[12];
  const float* b_hh      = (const float*)d_in[13];
  const float* topic_h_w = (const float*)d_in[14];
  const float* topic_h_b = (const float*)d_in[15];
  const float* topic_c_w = (const float*)d_in[16];
  const float* topic_c_b = (const float*)d_in[17];
  const float* stop_p_w  = (const float*)d_in[18];
  const float* stop_p_b  = (const float*)d_in[19];
  const float* stop_c_w  = (const float*)d_in[20];
  const float* stop_c_b  = (const float*)d_in[21];
  const float* final_w   = (const float*)d_in[22];
  const float* final_b   = (const float*)d_in[23];

  uint8_t* wsp = (uint8_t*)d_ws;
  size_t off = 0;
  auto take = [&](size_t bytes) -> void* {
    void* p = wsp + off;
    off = (off + bytes + 255) & ~(size_t)255;
    return p;
  };

  short* encproj = (short*)take((size_t)B_*NPOS*A_*2);  // 51.4 MB
  short* encw    = (short*)take((size_t)A_*D_*2);
  short* ctxw    = (short*)take((size_t)SI_*D_*2);
  short* w1      = (short*)take((size_t)N1*H_*2);
  short* w2      = (short*)take((size_t)N2*SI_*2);
  short* w3      = (short*)take((size_t)N3*H_*2);
  float* bias1   = (float*)take((size_t)N1*4);
  float* bias2   = (float*)take((size_t)N2*4);
  float* bias3   = (float*)take((size_t)N3*4);
  short* hbf     = (short*)take((size_t)B_*H_*2);
  float* cst     = (float*)take((size_t)B_*H_*4);
  float* g1      = (float*)take((size_t)B_*N1*4);
  float* g3      = (float*)take((size_t)B_*N2*4);
  float* g5      = (float*)take((size_t)B_*N3*4);
  short* attb    = (short*)take((size_t)B_*D_*2);
  short* ctxb    = (short*)take((size_t)B_*SI_*2);
  const size_t base = off;
  short* v16 = (short*)(wsp + off);
  const size_t v16_bytes = (size_t)B_ * NPOS * D_ * 2;  // 205.5 MB
  const bool full = (ws_size >= base + v16_bytes);

  auto cvt = [&](const float* src, short* dst, long n) {
    long blocks = (n / 8 + 255) / 256;
    if (blocks > 4096) blocks = 4096;
    cvt_k<<<(int)blocks, 256, 0, stream>>>(src, dst, n);
  };

  // weights -> bf16 (concatenated), biases -> concatenated f32
  cvt(enc_att_w, encw, (long)A_ * D_);
  cvt(ctx_w,     ctxw, (long)SI_ * D_);
  cvt(dec_att_w, w1,                         (long)512  * 1024);
  cvt(w_hh,      w1 + (size_t)512  * 1024,   (long)4096 * 1024);
  cvt(stop_p_w,  w1 + (size_t)4608 * 1024,   (long)256  * 1024);
  cvt(w_ih,      w2,                         (long)4096 * 1024);
  cvt(topic_c_w, w2 + (size_t)4096 * 1024,   (long)1024 * 1024);
  cvt(topic_h_w, w3,                         (long)1024 * 1024);
  cvt(stop_c_w,  w3 + (size_t)1024 * 1024,   (long)256  * 1024);
  hipMemcpyAsync(bias1,        dec_att_b, 512 * 4,  hipMemcpyDeviceToDevice, stream);
  hipMemcpyAsync(bias1 + 512,  b_hh,      4096 * 4, hipMemcpyDeviceToDevice, stream);
  hipMemcpyAsync(bias1 + 4608, stop_p_b,  256 * 4,  hipMemcpyDeviceToDevice, stream);
  hipMemcpyAsync(bias2,        b_ih,      4096 * 4, hipMemcpyDeviceToDevice, stream);
  hipMemcpyAsync(bias2 + 4096, topic_c_b, 1024 * 4, hipMemcpyDeviceToDevice, stream);
  hipMemcpyAsync(bias3,        topic_h_b, 1024 * 4, hipMemcpyDeviceToDevice, stream);
  hipMemcpyAsync(bias3 + 1024, stop_c_b,  256 * 4,  hipMemcpyDeviceToDevice, stream);
  hipMemsetAsync(hbf, 0, (size_t)B_ * H_ * 2, stream);
  hipMemsetAsync(cst, 0, (size_t)B_ * H_ * 4, stream);

  // enc_proj = v @ enc_att_w^T + b  (bf16 out)
  const int Mrows = B_ * NPOS;  // 50176 = 392 * 128
  if (full) {
    cvt(vis, v16, (long)Mrows * D_);
    gemm_bt_k<1><<<dim3(Mrows / 128, A_ / 128), 256, 0, stream>>>(
        v16, encw, enc_att_b, encproj, Mrows, A_, D_);
  } else {
    // chunked: convert a slab of v rows, GEMM it, repeat
    const size_t avail = (ws_size > base) ? ws_size - base : 0;
    int dt = 1;
    const int cand[] = {56, 28, 14, 8, 7, 4, 2, 1};
    for (int c : cand) {
      if ((392 % c) == 0 && (size_t)c * 128 * D_ * 2 <= avail) { dt = c; break; }
    }
    short* vchunk = (short*)(wsp + base);
    const int CR = dt * 128;
    for (int s = 0; s < Mrows; s += CR) {
      cvt(vis + (size_t)s * D_, vchunk, (long)CR * D_);
      gemm_bt_k<1><<<dim3(dt, A_ / 128), 256, 0, stream>>>(
          vchunk, encw, enc_att_b, encproj + (size_t)s * A_, CR, A_, D_);
    }
  }

  // sequential sentence-LSTM steps
  for (int t = 0; t < T_; ++t) {
    // g1 = h_prev @ [dec_att_w; w_hh; stop_p_w]^T + [dec_att_b; b_hh; stop_p_b]
    gemm_bt_k<0><<<dim3(B_ / 128, N1 / 128), 256, 0, stream>>>(hbf, w1, bias1, g1, B_, N1, H_);
    // attention (dec comes from g1 cols [0,512))
    if (full) att_k<1><<<B_, 256, 0, stream>>>(v16, encproj, g1, full_att_w, attb);
    else      att_k<0><<<B_, 256, 0, stream>>>(vis, encproj, g1, full_att_w, attb);
    // ctx = att_out @ ctx_w^T + ctx_b  (bf16 out, only consumed by GEMMs)
    gemm_bt_k<1><<<dim3(B_ / 128, SI_ / 128), 256, 0, stream>>>(attb, ctxw, ctx_b, ctxb, B_, SI_, D_);
    // g3 = ctx @ [w_ih; topic_c_w]^T + [b_ih; topic_c_b]
    gemm_bt_k<0><<<dim3(B_ / 128, N2 / 128), 256, 0, stream>>>(ctxb, w2, bias2, g3, B_, N2, SI_);
    // LSTM cell: updates c (f32) and h (bf16)
    lstm_k<<<(B_ * H_) / 256, 256, 0, stream>>>(g1, g3, cst, hbf);
    // g5 = h_new @ [topic_h_w; stop_c_w]^T + [topic_h_b; stop_c_b]
    gemm_bt_k<0><<<dim3(B_ / 128, N3 / 128), 256, 0, stream>>>(hbf, w3, bias3, g5, B_, N3, H_);
    // topic = tanh(g5[:, :1024] + g3[:, 4096:]);  p = tanh(g1[:,4608:] + g5[:,1024:]) @ final_w^T + final_b
    final_k<<<B_, 256, 0, stream>>>(g1, g3, g5, final_w, final_b,
                                    (float*)d_out, (float*)d_out + (size_t)B_ * T_ * WI_, t);
  }
}

// Round 2
// 1726.827 us; speedup vs baseline: 1.5652x; 1.5652x over previous
//
#include <hip/hip_runtime.h>
#include <cstdint>

// ---- problem constants ----
#define B_   256
#define NPOS 196        // 14*14
#define D_   2048
#define H_   1024
#define A_   512
#define T_   10

// W13 = [dec_att_w(512); w_hh(4096); stop_p_w(256); topic_h_w(1024); stop_c_w(256)]
#define N13  6144
#define OFF_DEC    0
#define OFF_WHH    512
#define OFF_STOPP  4608
#define OFF_TOPICH 4864
#define OFF_STOPC  5888
// Wc = [w_ih(4096); topic_c_w(1024)] @ ctx_w   -> [5120 x 2048]
#define NC   5120

typedef __attribute__((ext_vector_type(8))) short bf16x8;
typedef __attribute__((ext_vector_type(4))) short bf16x4;
typedef __attribute__((ext_vector_type(4))) float f32x4;

__device__ __forceinline__ float b2f(short s) {
  union { unsigned int u; float f; } c;
  c.u = ((unsigned int)(unsigned short)s) << 16;
  return c.f;
}
__device__ __forceinline__ short f2b(float f) {
  union { float f; unsigned int u; } c; c.f = f;
  unsigned int u = c.u + 0x7fffu + ((c.u >> 16) & 1u);  // RNE
  return (short)(u >> 16);
}
__device__ __forceinline__ float fast_tanh(float x) {
  float a = fabsf(x);
  float e = __expf(-2.f * a);
  float t = __fdividef(1.f - e, 1.f + e);
  return x < 0.f ? -t : t;
}
__device__ __forceinline__ float fast_sigm(float x) {
  return __fdividef(1.f, 1.f + __expf(-x));
}

#define GLDS16(g, l) __builtin_amdgcn_global_load_lds( \
    (const __attribute__((address_space(1))) void*)(g), \
    (__attribute__((address_space(3))) void*)(l), 16, 0, 0)

// ---------------- fp32 -> bf16 convert ----------------
__global__ void cvt_k(const float* __restrict__ in, short* __restrict__ out, long n)
{
  long i = ((long)blockIdx.x * blockDim.x + threadIdx.x) * 8;
  long stride = (long)gridDim.x * blockDim.x * 8;
  for (; i < n; i += stride) {
    float4 a = *(const float4*)(in + i);
    float4 b = *(const float4*)(in + i + 4);
    bf16x8 o;
    o[0]=f2b(a.x); o[1]=f2b(a.y); o[2]=f2b(a.z); o[3]=f2b(a.w);
    o[4]=f2b(b.x); o[5]=f2b(b.y); o[6]=f2b(b.z); o[7]=f2b(b.w);
    *(bf16x8*)(out + i) = o;
  }
}

// ---------------- transpose + convert: in[R][C] f32 -> out[C][R] bf16 ----------------
__global__ __launch_bounds__(256) void transpose_cvt_k(
    const float* __restrict__ in, short* __restrict__ out, int R, int C)
{
  __shared__ float t[32][33];
  const int r0 = blockIdx.y * 32, c0 = blockIdx.x * 32;
  const int tx = threadIdx.x & 31, ty = threadIdx.x >> 5;  // 32x8
  #pragma unroll
  for (int i = 0; i < 32; i += 8)
    t[ty + i][tx] = in[(size_t)(r0 + ty + i) * C + c0 + tx];
  __syncthreads();
  #pragma unroll
  for (int i = 0; i < 32; i += 8)
    out[(size_t)(c0 + ty + i) * R + r0 + tx] = f2b(t[tx][ty + i]);
}

// ---------------- bias_c[r] = b[r] + dot(w2[r,:], ctx_b)  (fp32, one wave/row) ----------
__global__ __launch_bounds__(256) void biasc_k(
    const float* __restrict__ w_ih, const float* __restrict__ b_ih,
    const float* __restrict__ topic_c_w, const float* __restrict__ topic_c_b,
    const float* __restrict__ ctx_b, float* __restrict__ out)
{
  const int r = blockIdx.x * 4 + (threadIdx.x >> 6);
  const int l = threadIdx.x & 63;
  const float* wr; float bb;
  if (r < 4096) { wr = w_ih + (size_t)r * 1024;          bb = b_ih[r]; }
  else          { wr = topic_c_w + (size_t)(r - 4096) * 1024; bb = topic_c_b[r - 4096]; }
  float s = 0.f;
  #pragma unroll
  for (int k = 0; k < 16; ++k) s += wr[l + 64 * k] * ctx_b[l + 64 * k];
  #pragma unroll
  for (int o = 32; o; o >>= 1) s += __shfl_down(s, o);
  if (!l) out[r] = s + bb;
}

// ---------------- g[b][:] = bias  (t=0 init: h=0 so h@W13 = bias13) ----------------
__global__ __launch_bounds__(256) void initg_k(const float* __restrict__ bias, float* __restrict__ g)
{
  g[(size_t)blockIdx.y * N13 + blockIdx.x * 256 + threadIdx.x] = bias[blockIdx.x * 256 + threadIdx.x];
}

// ---------------- bf16 MFMA GEMM: C[M,N] = A[M,K] * B[N,K]^T + bias[N] ----------------
// BM=128 fixed, BN in {64,128}; grid = (N/BN, M/128) so consecutive blocks share A-panel.
template<int OUTBF16, int BN>
__global__ __launch_bounds__(256) void gemm_bt_k(
    const short* __restrict__ Aptr, const short* __restrict__ Bptr,
    const float* __restrict__ bias, void* __restrict__ Cout,
    int M, int N, int K)
{
  constexpr int BNCH = BN / 8;        // 1KB chunks in B tile
  constexpr int TOT  = 16 + BNCH;     // + 16 A chunks
  constexpr int NW   = BN / 32;       // 16-col frags per wave
  __shared__ short As[128 * 64];
  __shared__ short Bs[BN * 64];
  const int tid = threadIdx.x;
  const int l = tid & 63, wv = tid >> 6;
  const int wr = wv >> 1, wc = wv & 1;
  const size_t m0 = (size_t)blockIdx.y * 128;
  const size_t n0 = (size_t)blockIdx.x * BN;
  const int srow = l >> 3, scol = (l & 7) * 8;
  const int lr = l & 15, lg = l >> 4;

  f32x4 acc[4][NW];
  #pragma unroll
  for (int i = 0; i < 4; ++i)
    #pragma unroll
    for (int j = 0; j < NW; ++j) acc[i][j] = (f32x4){0.f, 0.f, 0.f, 0.f};

  for (int k0 = 0; k0 < K; k0 += 64) {
    #pragma unroll
    for (int i = 0; i < TOT / 4; ++i) {
      const int c = i * 4 + wv;
      if (c < 16) {
        const int row = c * 8 + srow;
        GLDS16(Aptr + (m0 + row) * (size_t)K + k0 + scol, As + c * 512);
      } else {
        const int row = (c - 16) * 8 + srow;
        GLDS16(Bptr + (n0 + row) * (size_t)K + k0 + scol, Bs + (c - 16) * 512);
      }
    }
    __syncthreads();
    #pragma unroll
    for (int kk = 0; kk < 64; kk += 32) {
      bf16x8 af[4], bfr[NW];
      #pragma unroll
      for (int m = 0; m < 4; ++m)
        af[m] = *(const bf16x8*)(As + (wr * 64 + m * 16 + lr) * 64 + kk + lg * 8);
      #pragma unroll
      for (int n = 0; n < NW; ++n)
        bfr[n] = *(const bf16x8*)(Bs + (wc * (BN / 2) + n * 16 + lr) * 64 + kk + lg * 8);
      #pragma unroll
      for (int m = 0; m < 4; ++m)
        #pragma unroll
        for (int n = 0; n < NW; ++n)
          acc[m][n] = __builtin_amdgcn_mfma_f32_16x16x32_bf16(af[m], bfr[n], acc[m][n], 0, 0, 0);
    }
    __syncthreads();
  }

  #pragma unroll
  for (int m = 0; m < 4; ++m) {
    const size_t row = m0 + wr * 64 + m * 16 + lg * 4;
    #pragma unroll
    for (int n = 0; n < NW; ++n) {
      const size_t col = n0 + wc * (BN / 2) + n * 16 + lr;
      const float bv = bias[col];
      #pragma unroll
      for (int r = 0; r < 4; ++r) {
        const float v = acc[m][n][r] + bv;
        if (OUTBF16) ((short*)Cout)[(row + r) * (size_t)N + col] = f2b(v);
        else         ((float*)Cout)[(row + r) * (size_t)N + col] = v;
      }
    }
  }
}

// ---------------- attention: logits -> softmax -> att_out; one block (512 thr) per batch ----
template<int V16>
__global__ __launch_bounds__(512) void att_k(
    const void* __restrict__ vptr,       // bf16 v16 (V16) or fp32 vis
    const short* __restrict__ encp,      // [B,196,512] bf16
    const float* __restrict__ gprev,     // dec = cols [0,512) of [B,N13] f32
    const float* __restrict__ fullw,     // [512] f32
    short* __restrict__ attout)          // [B,2048] bf16
{
  const int b = blockIdx.x, tid = threadIdx.x;
  const int l = tid & 63, wv = tid >> 6;       // 8 waves
  __shared__ float dec_s[A_], fw_s[A_], sc[NPOS], red[16];

  if (tid < A_) {
    dec_s[tid] = gprev[(size_t)b * N13 + tid];
    fw_s[tid]  = fullw[tid];
  }
  __syncthreads();

  const short* ep = encp + (size_t)b * NPOS * A_;
  for (int n = wv; n < NPOS; n += 8) {
    bf16x8 e = *(const bf16x8*)(ep + (size_t)n * A_ + l * 8);
    float s = 0.f;
    #pragma unroll
    for (int j = 0; j < 8; ++j)
      s += fast_tanh(b2f(e[j]) + dec_s[l * 8 + j]) * fw_s[l * 8 + j];
    #pragma unroll
    for (int o = 32; o; o >>= 1) s += __shfl_down(s, o);
    if (!l) sc[n] = s;
  }
  __syncthreads();

  float lm = (tid < NPOS) ? sc[tid] : -3e38f;
  #pragma unroll
  for (int o = 32; o; o >>= 1) lm = fmaxf(lm, __shfl_down(lm, o));
  if (!l) red[wv] = lm;
  __syncthreads();
  float mx = red[0];
  #pragma unroll
  for (int i = 1; i < 8; ++i) mx = fmaxf(mx, red[i]);
  const float ev = (tid < NPOS) ? __expf(sc[tid] - mx) : 0.f;
  float es = ev;
  #pragma unroll
  for (int o = 32; o; o >>= 1) es += __shfl_down(es, o);
  if (!l) red[8 + wv] = es;
  __syncthreads();
  float tot = red[8];
  #pragma unroll
  for (int i = 1; i < 8; ++i) tot += red[8 + i];
  const float inv = __fdividef(1.f, tot);
  if (tid < NPOS) sc[tid] = ev * inv;
  __syncthreads();

  // PV: thread owns d = tid*4 .. +3
  float acc[4] = {0.f, 0.f, 0.f, 0.f};
  const int d0 = tid * 4;
  if (V16) {
    const short* vb = (const short*)vptr + (size_t)b * NPOS * D_ + d0;
    #pragma unroll 4
    for (int n = 0; n < NPOS; ++n) {
      const float s = sc[n];
      bf16x4 vv = *(const bf16x4*)(vb + (size_t)n * D_);
      #pragma unroll
      for (int j = 0; j < 4; ++j) acc[j] += s * b2f(vv[j]);
    }
  } else {
    const float* vf = (const float*)vptr + (size_t)b * NPOS * D_ + d0;
    #pragma unroll 2
    for (int n = 0; n < NPOS; ++n) {
      const float s = sc[n];
      float4 vv = *(const float4*)(vf + (size_t)n * D_);
      acc[0] += s * vv.x; acc[1] += s * vv.y; acc[2] += s * vv.z; acc[3] += s * vv.w;
    }
  }
  bf16x4 o4;
  #pragma unroll
  for (int j = 0; j < 4; ++j) o4[j] = f2b(acc[j]);
  *(bf16x4*)(attout + (size_t)b * D_ + d0) = o4;
}

// ---------------- LSTM cell ----------------
__global__ __launch_bounds__(256) void lstm_k(
    const float* __restrict__ gprev, const float* __restrict__ g3,
    float* __restrict__ c, short* __restrict__ hbf)
{
  const int idx = blockIdx.x * 256 + threadIdx.x;   // 0 .. B*H-1
  const int b = idx >> 10, j = idx & 1023;
  const float* gi = g3 + (size_t)b * NC;
  const float* gh = gprev + (size_t)b * N13 + OFF_WHH;
  const float iv = gi[j]        + gh[j];
  const float fv = gi[1024 + j] + gh[1024 + j];
  const float gv = gi[2048 + j] + gh[2048 + j];
  const float ov = gi[3072 + j] + gh[3072 + j];
  const float cn = fast_sigm(fv) * c[idx] + fast_sigm(iv) * fast_tanh(gv);
  const float hn = fast_sigm(ov) * fast_tanh(cn);
  c[idx] = cn;
  hbf[idx] = f2b(hn);
}

// ---------------- epilogue: topic + stop-path p ----------------
__global__ __launch_bounds__(256) void final_k(
    const float* __restrict__ gprev, const float* __restrict__ gcur,
    const float* __restrict__ g3, const float* __restrict__ fw,
    const float* __restrict__ fb, float* __restrict__ out_t,
    float* __restrict__ out_p, int t)
{
  const int b = blockIdx.x, tid = threadIdx.x;
  const float* t3 = g3 + (size_t)b * NC + 4096;
  const float* tc = gcur + (size_t)b * N13;
  const float* tp = gprev + (size_t)b * N13;
  float* ot = out_t + (size_t)b * (T_ * 1024) + (size_t)t * 1024;
  #pragma unroll
  for (int i = 0; i < 4; ++i) {
    const int j = tid + i * 256;
    ot[j] = fast_tanh(tc[OFF_TOPICH + j] + t3[j]);
  }
  __shared__ float pp[256];
  pp[tid] = fast_tanh(tp[OFF_STOPP + tid] + tc[OFF_STOPC + tid]);
  __syncthreads();
  const int wv = tid >> 6, l = tid & 63;
  if (wv < 2) {
    float s = 0.f;
    #pragma unroll
    for (int k = 0; k < 4; ++k) s += pp[l + 64 * k] * fw[wv * 256 + l + 64 * k];
    #pragma unroll
    for (int o = 32; o; o >>= 1) s += __shfl_down(s, o);
    if (!l) out_p[(size_t)b * (T_ * 2) + t * 2 + wv] = s + fb[wv];
  }
}

// ---------------- host ----------------
extern "C" void kernel_launch(void* const* d_in, const int* in_sizes, int n_in,
                              void* d_out, int out_size, void* d_ws, size_t ws_size,
                              hipStream_t stream)
{
  const float* vis       = (const float*)d_in[0];
  const float* enc_att_w = (const float*)d_in[2];
  const float* enc_att_b = (const float*)d_in[3];
  const float* dec_att_w = (const float*)d_in[4];
  const float* dec_att_b = (const float*)d_in[5];
  const float* full_att_w= (const float*)d_in[6];
  const float* ctx_w     = (const float*)d_in[8];
  const float* ctx_b     = (const float*)d_in[9];
  const float* w_ih      = (const float*)d_in[10];
  const float* b_ih      = (const float*)d_in[11];
  const float* w_hh      = (const float*)d_in[12];
  const float* b_hh      = (const float*)d_in[13];
  const float* topic_h_w = (const float*)d_in[14];
  const float* topic_h_b = (const float*)d_in[15];
  const float* topic_c_w = (const float*)d_in[16];
  const float* topic_c_b = (const float*)d_in[17];
  const float* stop_p_w  = (const float*)d_in[18];
  const float* stop_p_b  = (const float*)d_in[19];
  const float* stop_c_w  = (const float*)d_in[20];
  const float* stop_c_b  = (const float*)d_in[21];
  const float* final_w   = (const float*)d_in[22];
  const float* final_b   = (const float*)d_in[23];

  uint8_t* wsp = (uint8_t*)d_ws;
  size_t off = 0;
  auto take = [&](size_t bytes) -> void* {
    void* p = wsp + off;
    off = (off + bytes + 255) & ~(size_t)255;
    return p;
  };

  short* encproj = (short*)take((size_t)B_ * NPOS * A_ * 2);   // 51.4 MB
  short* encw    = (short*)take((size_t)A_ * D_ * 2);
  short* w2cat   = (short*)take((size_t)NC * 1024 * 2);        // [w_ih; topic_c_w] bf16
  short* ctxwT   = (short*)take((size_t)D_ * 1024 * 2);        // ctx_w^T bf16
  short* Wc      = (short*)take((size_t)NC * D_ * 2);          // composed [5120 x 2048]
  short* w13     = (short*)take((size_t)N13 * H_ * 2);
  float* biasc   = (float*)take((size_t)NC * 4);
  float* bias13  = (float*)take((size_t)N13 * 4);
  float* zeros   = (float*)take((size_t)D_ * 4);
  short* hbf     = (short*)take((size_t)B_ * H_ * 2);
  float* cst     = (float*)take((size_t)B_ * H_ * 4);
  float* gA      = (float*)take((size_t)B_ * N13 * 4);
  float* gB      = (float*)take((size_t)B_ * N13 * 4);
  float* g3      = (float*)take((size_t)B_ * NC * 4);
  short* attb    = (short*)take((size_t)B_ * D_ * 2);
  const size_t base = off;
  short* v16 = (short*)(wsp + off);
  const size_t v16_bytes = (size_t)B_ * NPOS * D_ * 2;         // 205.5 MB
  const bool full = (ws_size >= base + v16_bytes);

  auto cvt = [&](const float* src, short* dst, long n) {
    long blocks = (n / 8 + 255) / 256;
    if (blocks > 4096) blocks = 4096;
    cvt_k<<<(int)blocks, 256, 0, stream>>>(src, dst, n);
  };

  // ---- one-time weight prep ----
  cvt(enc_att_w, encw, (long)A_ * D_);
  cvt(w_ih,      w2cat,                       (long)4096 * 1024);
  cvt(topic_c_w, w2cat + (size_t)4096 * 1024, (long)1024 * 1024);
  transpose_cvt_k<<<dim3(D_ / 32, 1024 / 32), 256, 0, stream>>>(ctx_w, ctxwT, 1024, D_);
  hipMemsetAsync(zeros, 0, (size_t)D_ * 4, stream);
  // Wc[r,d] = sum_s w2cat[r,s] * ctx_w[s,d]
  gemm_bt_k<1, 128><<<dim3(D_ / 128, NC / 128), 256, 0, stream>>>(
      w2cat, ctxwT, zeros, Wc, NC, D_, 1024);
  biasc_k<<<NC / 4, 256, 0, stream>>>(w_ih, b_ih, topic_c_w, topic_c_b, ctx_b, biasc);

  cvt(dec_att_w, w13 + (size_t)OFF_DEC    * 1024, (long)512  * 1024);
  cvt(w_hh,      w13 + (size_t)OFF_WHH    * 1024, (long)4096 * 1024);
  cvt(stop_p_w,  w13 + (size_t)OFF_STOPP  * 1024, (long)256  * 1024);
  cvt(topic_h_w, w13 + (size_t)OFF_TOPICH * 1024, (long)1024 * 1024);
  cvt(stop_c_w,  w13 + (size_t)OFF_STOPC  * 1024, (long)256  * 1024);
  hipMemcpyAsync(bias13 + OFF_DEC,    dec_att_b, 512 * 4,  hipMemcpyDeviceToDevice, stream);
  hipMemcpyAsync(bias13 + OFF_WHH,    b_hh,      4096 * 4, hipMemcpyDeviceToDevice, stream);
  hipMemcpyAsync(bias13 + OFF_STOPP,  stop_p_b,  256 * 4,  hipMemcpyDeviceToDevice, stream);
  hipMemcpyAsync(bias13 + OFF_TOPICH, topic_h_b, 1024 * 4, hipMemcpyDeviceToDevice, stream);
  hipMemcpyAsync(bias13 + OFF_STOPC,  stop_c_b,  256 * 4,  hipMemcpyDeviceToDevice, stream);
  hipMemsetAsync(hbf, 0, (size_t)B_ * H_ * 2, stream);
  hipMemsetAsync(cst, 0, (size_t)B_ * H_ * 4, stream);
  initg_k<<<dim3(N13 / 256, B_), 256, 0, stream>>>(bias13, gA);   // h=0 -> g = bias13

  // ---- enc_proj = v @ enc_att_w^T + b ----
  const int Mrows = B_ * NPOS;  // 50176 = 392*128
  if (full) {
    cvt(vis, v16, (long)Mrows * D_);
    gemm_bt_k<1, 128><<<dim3(A_ / 128, Mrows / 128), 256, 0, stream>>>(
        v16, encw, enc_att_b, encproj, Mrows, A_, D_);
  } else {
    const size_t avail = (ws_size > base) ? ws_size - base : 0;
    int dt = 1;
    const int cand[] = {56, 28, 14, 8, 7, 4, 2, 1};
    for (int c : cand)
      if ((392 % c) == 0 && (size_t)c * 128 * D_ * 2 <= avail) { dt = c; break; }
    short* vchunk = (short*)(wsp + base);
    const int CR = dt * 128;
    for (int s = 0; s < Mrows; s += CR) {
      cvt(vis + (size_t)s * D_, vchunk, (long)CR * D_);
      gemm_bt_k<1, 128><<<dim3(A_ / 128, dt), 256, 0, stream>>>(
          vchunk, encw, enc_att_b, encproj + (size_t)s * A_, CR, A_, D_);
    }
  }

  // ---- sequential sentence-LSTM steps (5 kernels/step) ----
  float* gP = gA; float* gC = gB;
  for (int t = 0; t < T_; ++t) {
    if (full) att_k<1><<<B_, 512, 0, stream>>>(v16, encproj, gP, full_att_w, attb);
    else      att_k<0><<<B_, 512, 0, stream>>>(vis, encproj, gP, full_att_w, attb);
    // gates+topic_c directly from att_out through the composed weight
    gemm_bt_k<0, 64><<<dim3(NC / 64, B_ / 128), 256, 0, stream>>>(
        attb, Wc, biasc, g3, B_, NC, D_);
    lstm_k<<<(B_ * H_) / 256, 256, 0, stream>>>(gP, g3, cst, hbf);
    // h_new @ [dec; w_hh; stop_p; topic_h; stop_c]^T + bias13
    gemm_bt_k<0, 64><<<dim3(N13 / 64, B_ / 128), 256, 0, stream>>>(
        hbf, w13, bias13, gC, B_, N13, H_);
    final_k<<<B_, 256, 0, stream>>>(gP, gC, g3, final_w, final_b,
                                    (float*)d_out, (float*)d_out + (size_t)B_ * T_ * 1024, t);
    float* tmp = gP; gP = gC; gC = tmp;
  }
}

// Round 4
// 1369.757 us; speedup vs baseline: 1.9733x; 1.2607x over previous
//
#include <hip/hip_runtime.h>
#include <cstdint>

// ---- problem constants ----
#define B_   256
#define NPOS 196        // 14*14
#define D_   2048
#define H_   1024
#define A_   512
#define T_   10

// W13 = [dec_att_w(512); w_hh(4096); stop_p_w(256); topic_h_w(1024); stop_c_w(256)]
#define N13  6144
#define OFF_DEC    0
#define OFF_WHH    512
#define OFF_STOPP  4608
#define OFF_TOPICH 4864
#define OFF_STOPC  5888
// Wc = [w_ih(4096); topic_c_w(1024)] @ ctx_w   -> [5120 x 2048]
#define NC   5120

typedef __attribute__((ext_vector_type(8))) short bf16x8;
typedef __attribute__((ext_vector_type(4))) short bf16x4;
typedef __attribute__((ext_vector_type(4))) float f32x4;

__device__ __forceinline__ float b2f(short s) {
  union { unsigned int u; float f; } c;
  c.u = ((unsigned int)(unsigned short)s) << 16;
  return c.f;
}
__device__ __forceinline__ short f2b(float f) {
  union { float f; unsigned int u; } c; c.f = f;
  unsigned int u = c.u + 0x7fffu + ((c.u >> 16) & 1u);  // RNE
  return (short)(u >> 16);
}
__device__ __forceinline__ float fast_tanh(float x) {
  float a = fabsf(x);
  float e = __expf(-2.f * a);
  float t = __fdividef(1.f - e, 1.f + e);
  return x < 0.f ? -t : t;
}
__device__ __forceinline__ float fast_sigm(float x) {
  return __fdividef(1.f, 1.f + __expf(-x));
}

#define GLDS16(g, l) __builtin_amdgcn_global_load_lds( \
    (const __attribute__((address_space(1))) void*)(g), \
    (__attribute__((address_space(3))) void*)(l), 16, 0, 0)

// ---------------- pass 1: vis -> v16 bf16, and global absmax(v16) ----------------
__global__ __launch_bounds__(256) void cvt_v_k(
    const float* __restrict__ in, short* __restrict__ v16,
    unsigned int* __restrict__ maxbuf, long n)
{
  long i = ((long)blockIdx.x * blockDim.x + threadIdx.x) * 8;
  const long stride = (long)gridDim.x * blockDim.x * 8;
  float m = 0.f;
  for (; i < n; i += stride) {
    float4 a = *(const float4*)(in + i);
    float4 b = *(const float4*)(in + i + 4);
    bf16x8 o;
    o[0]=f2b(a.x); o[1]=f2b(a.y); o[2]=f2b(a.z); o[3]=f2b(a.w);
    o[4]=f2b(b.x); o[5]=f2b(b.y); o[6]=f2b(b.z); o[7]=f2b(b.w);
    *(bf16x8*)(v16 + i) = o;
    #pragma unroll
    for (int j = 0; j < 8; ++j) m = fmaxf(m, fabsf(b2f(o[j])));
  }
  #pragma unroll
  for (int o = 32; o; o >>= 1) m = fmaxf(m, __shfl_down(m, o));
  __shared__ float red[4];
  const int l = threadIdx.x & 63, wv = threadIdx.x >> 6;
  if (!l) red[wv] = m;
  __syncthreads();
  if (threadIdx.x == 0) {
    float mm = fmaxf(fmaxf(red[0], red[1]), fmaxf(red[2], red[3]));
    atomicMax(maxbuf, __float_as_uint(mm));   // positive floats order as uints
  }
}

// ---------------- pass 2: v16 -> int8 (biased u8), scale = max/127 ----------------
__global__ __launch_bounds__(256) void quant_v_k(
    const short* __restrict__ v16, unsigned char* __restrict__ v8,
    const unsigned int* __restrict__ maxbuf, long n)
{
  const float mv = __uint_as_float(*maxbuf);
  const float sinv = __fdividef(127.f, fmaxf(mv, 1e-20f));
  long i = ((long)blockIdx.x * blockDim.x + threadIdx.x) * 8;
  const long stride = (long)gridDim.x * blockDim.x * 8;
  for (; i < n; i += stride) {
    bf16x8 o = *(const bf16x8*)(v16 + i);
    unsigned int w0 = 0, w1 = 0;
    #pragma unroll
    for (int j = 0; j < 4; ++j) {
      float q = fminf(fmaxf(rintf(b2f(o[j]) * sinv), -127.f), 127.f) + 128.f;
      w0 |= ((unsigned int)(int)q) << (8 * j);
    }
    #pragma unroll
    for (int j = 0; j < 4; ++j) {
      float q = fminf(fmaxf(rintf(b2f(o[4 + j]) * sinv), -127.f), 127.f) + 128.f;
      w1 |= ((unsigned int)(int)q) << (8 * j);
    }
    uint2 pk; pk.x = w0; pk.y = w1;
    *(uint2*)(v8 + i) = pk;
  }
}

// ---------------- plain fp32 -> bf16 (chunked fallback path) ----------------
__global__ void cvt_k(const float* __restrict__ in, short* __restrict__ out, long n)
{
  long i = ((long)blockIdx.x * blockDim.x + threadIdx.x) * 8;
  const long stride = (long)gridDim.x * blockDim.x * 8;
  for (; i < n; i += stride) {
    float4 a = *(const float4*)(in + i);
    float4 b = *(const float4*)(in + i + 4);
    bf16x8 o;
    o[0]=f2b(a.x); o[1]=f2b(a.y); o[2]=f2b(a.z); o[3]=f2b(a.w);
    o[4]=f2b(b.x); o[5]=f2b(b.y); o[6]=f2b(b.z); o[7]=f2b(b.w);
    *(bf16x8*)(out + i) = o;
  }
}

// ---------------- batched weight cvt: 8 segments, 2048 elems/block ----------------
struct SegTab {
  const float* src[8];
  short* dst[8];
  int cum[9];
};
__global__ __launch_bounds__(256) void cvt_multi_k(SegTab t)
{
  int seg = 0;
  #pragma unroll
  for (int s = 0; s < 7; ++s) seg += (int)(blockIdx.x >= (unsigned)t.cum[s + 1]);
  const long i = ((long)(blockIdx.x - t.cum[seg]) * 256 + threadIdx.x) * 8;
  const float* in = t.src[seg];
  float4 a = *(const float4*)(in + i);
  float4 b = *(const float4*)(in + i + 4);
  bf16x8 o;
  o[0]=f2b(a.x); o[1]=f2b(a.y); o[2]=f2b(a.z); o[3]=f2b(a.w);
  o[4]=f2b(b.x); o[5]=f2b(b.y); o[6]=f2b(b.z); o[7]=f2b(b.w);
  *(bf16x8*)(t.dst[seg] + i) = o;
}

// ---------------- transpose + convert: in[R][C] f32 -> out[C][R] bf16 ----------------
__global__ __launch_bounds__(256) void transpose_cvt_k(
    const float* __restrict__ in, short* __restrict__ out, int R, int C)
{
  __shared__ float t[32][33];
  const int r0 = blockIdx.y * 32, c0 = blockIdx.x * 32;
  const int tx = threadIdx.x & 31, ty = threadIdx.x >> 5;
  #pragma unroll
  for (int i = 0; i < 32; i += 8)
    t[ty + i][tx] = in[(size_t)(r0 + ty + i) * C + c0 + tx];
  __syncthreads();
  #pragma unroll
  for (int i = 0; i < 32; i += 8)
    out[(size_t)(c0 + ty + i) * R + r0 + tx] = f2b(t[tx][ty + i]);
}

// ---------------- bias_c[r] = b[r] + dot(w2[r,:], ctx_b) ----------------
__global__ __launch_bounds__(256) void biasc_k(
    const float* __restrict__ w_ih, const float* __restrict__ b_ih,
    const float* __restrict__ topic_c_w, const float* __restrict__ topic_c_b,
    const float* __restrict__ ctx_b, float* __restrict__ out)
{
  const int r = blockIdx.x * 4 + (threadIdx.x >> 6);
  const int l = threadIdx.x & 63;
  const float* wr; float bb;
  if (r < 4096) { wr = w_ih + (size_t)r * 1024;               bb = b_ih[r]; }
  else          { wr = topic_c_w + (size_t)(r - 4096) * 1024; bb = topic_c_b[r - 4096]; }
  float s = 0.f;
  #pragma unroll
  for (int k = 0; k < 16; ++k) s += wr[l + 64 * k] * ctx_b[l + 64 * k];
  #pragma unroll
  for (int o = 32; o; o >>= 1) s += __shfl_down(s, o);
  if (!l) out[r] = s + bb;
}

// ---------------- assemble bias13 AND init gA rows (h0=0 -> g = bias13) ----------------
__global__ __launch_bounds__(256) void biasinit_k(
    const float* __restrict__ dec_att_b, const float* __restrict__ b_hh,
    const float* __restrict__ stop_p_b, const float* __restrict__ topic_h_b,
    const float* __restrict__ stop_c_b, float* __restrict__ bias13,
    float* __restrict__ gA)
{
  const int j = blockIdx.x * 256 + threadIdx.x;
  float v;
  if      (j < OFF_WHH)    v = dec_att_b[j];
  else if (j < OFF_STOPP)  v = b_hh[j - OFF_WHH];
  else if (j < OFF_TOPICH) v = stop_p_b[j - OFF_STOPP];
  else if (j < OFF_STOPC)  v = topic_h_b[j - OFF_TOPICH];
  else                     v = stop_c_b[j - OFF_STOPC];
  if (blockIdx.y == B_) bias13[j] = v;
  else                  gA[(size_t)blockIdx.y * N13 + j] = v;
}

// ---------------- bf16 MFMA GEMM: C[M,N] = A[M,K] * B[N,K]^T + bias[N] ----------------
template<int OUTBF16, int BN, int SWZ>
__global__ __launch_bounds__(256) void gemm_bt_k(
    const short* __restrict__ Aptr, const short* __restrict__ Bptr,
    const float* __restrict__ bias, void* __restrict__ Cout,
    int M, int N, int K)
{
  constexpr int TOT = 16 + BN / 8;
  constexpr int NW  = BN / 32;
  __shared__ short As[128 * 64];
  __shared__ short Bs[BN * 64];
  const int tid = threadIdx.x;
  const int l = tid & 63, wv = tid >> 6;
  const int wr = wv >> 1, wc = wv & 1;
  size_t m0, n0;
  if (SWZ) {  // grid (4, 392): A-panel blocks -> same XCD
    const int id  = blockIdx.y * 4 + blockIdx.x;
    const int xcd = id & 7, s = id >> 3;
    m0 = (size_t)(xcd * 49 + (s >> 2)) * 128;
    n0 = (size_t)(s & 3) * BN;
  } else {
    m0 = (size_t)blockIdx.y * 128;
    n0 = (size_t)blockIdx.x * BN;
  }
  const int srow = l >> 3, scol = (l & 7) * 8;
  const int lr = l & 15, lg = l >> 4;

  f32x4 acc[4][NW];
  #pragma unroll
  for (int i = 0; i < 4; ++i)
    #pragma unroll
    for (int j = 0; j < NW; ++j) acc[i][j] = (f32x4){0.f, 0.f, 0.f, 0.f};

  for (int k0 = 0; k0 < K; k0 += 64) {
    #pragma unroll
    for (int i = 0; i < TOT / 4; ++i) {
      const int c = i * 4 + wv;
      if (c < 16) {
        const int row = c * 8 + srow;
        GLDS16(Aptr + (m0 + row) * (size_t)K + k0 + scol, As + c * 512);
      } else {
        const int row = (c - 16) * 8 + srow;
        GLDS16(Bptr + (n0 + row) * (size_t)K + k0 + scol, Bs + (c - 16) * 512);
      }
    }
    __syncthreads();
    #pragma unroll
    for (int kk = 0; kk < 64; kk += 32) {
      bf16x8 af[4], bfr[NW];
      #pragma unroll
      for (int m = 0; m < 4; ++m)
        af[m] = *(const bf16x8*)(As + (wr * 64 + m * 16 + lr) * 64 + kk + lg * 8);
      #pragma unroll
      for (int n = 0; n < NW; ++n)
        bfr[n] = *(const bf16x8*)(Bs + (wc * (BN / 2) + n * 16 + lr) * 64 + kk + lg * 8);
      #pragma unroll
      for (int m = 0; m < 4; ++m)
        #pragma unroll
        for (int n = 0; n < NW; ++n)
          acc[m][n] = __builtin_amdgcn_mfma_f32_16x16x32_bf16(af[m], bfr[n], acc[m][n], 0, 0, 0);
    }
    __syncthreads();
  }

  #pragma unroll
  for (int m = 0; m < 4; ++m) {
    const size_t row = m0 + wr * 64 + m * 16 + lg * 4;
    #pragma unroll
    for (int n = 0; n < NW; ++n) {
      const size_t col = n0 + wc * (BN / 2) + n * 16 + lr;
      const float bv = bias[col];
      #pragma unroll
      for (int r = 0; r < 4; ++r) {
        const float v = acc[m][n][r] + bv;
        if (OUTBF16) ((short*)Cout)[(row + r) * (size_t)N + col] = f2b(v);
        else         ((float*)Cout)[(row + r) * (size_t)N + col] = v;
      }
    }
  }
}

// ---------------- scores: logits + softmax -> scbuf[b][196] (normalized) ----------------
__global__ __launch_bounds__(512) void scores_k(
    const short* __restrict__ encp,      // [B,196,512] bf16
    const float* __restrict__ gprev,     // dec = cols [0,512) of [B,N13] f32
    const float* __restrict__ fullw,     // [512] f32
    float* __restrict__ scbuf)           // [B,196] f32
{
  const int b = blockIdx.x, tid = threadIdx.x;
  const int l = tid & 63, wv = tid >> 6;       // 8 waves
  __shared__ float dec_s[A_], fw_s[A_], sc[NPOS], red[16];

  if (tid < A_) {
    dec_s[tid] = gprev[(size_t)b * N13 + tid];
    fw_s[tid]  = fullw[tid];
  }
  __syncthreads();

  const short* ep = encp + (size_t)b * NPOS * A_;
  for (int n = wv; n < NPOS; n += 8) {
    bf16x8 e = *(const bf16x8*)(ep + (size_t)n * A_ + l * 8);
    float s = 0.f;
    #pragma unroll
    for (int j = 0; j < 8; ++j)
      s += fast_tanh(b2f(e[j]) + dec_s[l * 8 + j]) * fw_s[l * 8 + j];
    #pragma unroll
    for (int o = 32; o; o >>= 1) s += __shfl_down(s, o);
    if (!l) sc[n] = s;
  }
  __syncthreads();

  float lm = (tid < NPOS) ? sc[tid] : -3e38f;
  #pragma unroll
  for (int o = 32; o; o >>= 1) lm = fmaxf(lm, __shfl_down(lm, o));
  if (!l) red[wv] = lm;
  __syncthreads();
  float mx = red[0];
  #pragma unroll
  for (int i = 1; i < 8; ++i) mx = fmaxf(mx, red[i]);
  const float ev = (tid < NPOS) ? __expf(sc[tid] - mx) : 0.f;
  float es = ev;
  #pragma unroll
  for (int o = 32; o; o >>= 1) es += __shfl_down(es, o);
  if (!l) red[8 + wv] = es;
  __syncthreads();
  float tot = red[8];
  #pragma unroll
  for (int i = 1; i < 8; ++i) tot += red[8 + i];
  if (tid < NPOS) scbuf[(size_t)b * NPOS + tid] = ev * __fdividef(1.f, tot);
}

// ---------------- PV: att_out = scores^T v ; grid (D_/512, B) ----------------
// VMODE 1: int8 v in ws (biased u8, affine scale); VMODE 0: fp32 vis.
template<int VMODE>
__global__ __launch_bounds__(256) void pv_k(
    const void* __restrict__ vptr, const float* __restrict__ scbuf,
    const unsigned int* __restrict__ maxbuf, short* __restrict__ attout)
{
  const int b = blockIdx.y;
  const int dbase = blockIdx.x * 512;
  const int tid = threadIdx.x;
  const int grp = tid >> 7;          // n parity
  const int dt = (tid & 127) * 4;    // dim within slice
  __shared__ float sc[NPOS];
  __shared__ float tmp[512];
  if (tid < NPOS) sc[tid] = scbuf[(size_t)b * NPOS + tid];
  __syncthreads();

  float a0 = 0.f, a1 = 0.f, a2 = 0.f, a3 = 0.f;
  if (VMODE == 1) {
    const unsigned char* vb = (const unsigned char*)vptr
        + (size_t)b * NPOS * D_ + dbase + dt;
    #pragma unroll 4
    for (int n = grp; n < NPOS; n += 2) {
      const float s = sc[n];
      const unsigned int w = *(const unsigned int*)(vb + (size_t)n * D_);
      a0 += s * (float)(w & 255u);
      a1 += s * (float)((w >> 8) & 255u);
      a2 += s * (float)((w >> 16) & 255u);
      a3 += s * (float)(w >> 24);
    }
  } else {
    const float* vf = (const float*)vptr + (size_t)b * NPOS * D_ + dbase + dt;
    #pragma unroll 2
    for (int n = grp; n < NPOS; n += 2) {
      const float s = sc[n];
      float4 vv = *(const float4*)(vf + (size_t)n * D_);
      a0 += s * vv.x; a1 += s * vv.y; a2 += s * vv.z; a3 += s * vv.w;
    }
  }
  if (grp == 1) {
    tmp[(tid & 127) * 4 + 0] = a0; tmp[(tid & 127) * 4 + 1] = a1;
    tmp[(tid & 127) * 4 + 2] = a2; tmp[(tid & 127) * 4 + 3] = a3;
  }
  __syncthreads();
  if (grp == 0) {
    a0 += tmp[dt + 0]; a1 += tmp[dt + 1]; a2 += tmp[dt + 2]; a3 += tmp[dt + 3];
    bf16x4 o4;
    if (VMODE == 1) {
      const float mv = __uint_as_float(*maxbuf);
      const float scale = mv * (1.f / 127.f);
      const float offs = -128.f * scale;       // sum(sc)=1
      o4[0] = f2b(a0 * scale + offs); o4[1] = f2b(a1 * scale + offs);
      o4[2] = f2b(a2 * scale + offs); o4[3] = f2b(a3 * scale + offs);
    } else {
      o4[0] = f2b(a0); o4[1] = f2b(a1); o4[2] = f2b(a2); o4[3] = f2b(a3);
    }
    *(bf16x4*)(attout + (size_t)b * D_ + dbase + dt) = o4;
  }
}

// ---------------- LSTM cell ----------------
__global__ __launch_bounds__(256) void lstm_k(
    const float* __restrict__ gprev, const float* __restrict__ g3,
    float* __restrict__ c, short* __restrict__ hbf)
{
  const int idx = blockIdx.x * 256 + threadIdx.x;
  const int b = idx >> 10, j = idx & 1023;
  const float* gi = g3 + (size_t)b * NC;
  const float* gh = gprev + (size_t)b * N13 + OFF_WHH;
  const float iv = gi[j]        + gh[j];
  const float fv = gi[1024 + j] + gh[1024 + j];
  const float gv = gi[2048 + j] + gh[2048 + j];
  const float ov = gi[3072 + j] + gh[3072 + j];
  const float cn = fast_sigm(fv) * c[idx] + fast_sigm(iv) * fast_tanh(gv);
  const float hn = fast_sigm(ov) * fast_tanh(cn);
  c[idx] = cn;
  hbf[idx] = f2b(hn);
}

// ---------------- epilogue: topic + stop-path p ----------------
__global__ __launch_bounds__(256) void final_k(
    const float* __restrict__ gprev, const float* __restrict__ gcur,
    const float* __restrict__ g3, const float* __restrict__ fw,
    const float* __restrict__ fb, float* __restrict__ out_t,
    float* __restrict__ out_p, int t)
{
  const int b = blockIdx.x, tid = threadIdx.x;
  const float* t3 = g3 + (size_t)b * NC + 4096;
  const float* tc = gcur + (size_t)b * N13;
  const float* tp = gprev + (size_t)b * N13;
  float* ot = out_t + (size_t)b * (T_ * 1024) + (size_t)t * 1024;
  #pragma unroll
  for (int i = 0; i < 4; ++i) {
    const int j = tid + i * 256;
    ot[j] = fast_tanh(tc[OFF_TOPICH + j] + t3[j]);
  }
  __shared__ float pp[256];
  pp[tid] = fast_tanh(tp[OFF_STOPP + tid] + tc[OFF_STOPC + tid]);
  __syncthreads();
  const int wv = tid >> 6, l = tid & 63;
  if (wv < 2) {
    float s = 0.f;
    #pragma unroll
    for (int k = 0; k < 4; ++k) s += pp[l + 64 * k] * fw[wv * 256 + l + 64 * k];
    #pragma unroll
    for (int o = 32; o; o >>= 1) s += __shfl_down(s, o);
    if (!l) out_p[(size_t)b * (T_ * 2) + t * 2 + wv] = s + fb[wv];
  }
}

// ---------------- host ----------------
extern "C" void kernel_launch(void* const* d_in, const int* in_sizes, int n_in,
                              void* d_out, int out_size, void* d_ws, size_t ws_size,
                              hipStream_t stream)
{
  const float* vis       = (const float*)d_in[0];
  const float* enc_att_w = (const float*)d_in[2];
  const float* enc_att_b = (const float*)d_in[3];
  const float* dec_att_w = (const float*)d_in[4];
  const float* dec_att_b = (const float*)d_in[5];
  const float* full_att_w= (const float*)d_in[6];
  const float* ctx_w     = (const float*)d_in[8];
  const float* ctx_b     = (const float*)d_in[9];
  const float* w_ih      = (const float*)d_in[10];
  const float* b_ih      = (const float*)d_in[11];
  const float* w_hh      = (const float*)d_in[12];
  const float* b_hh      = (const float*)d_in[13];
  const float* topic_h_w = (const float*)d_in[14];
  const float* topic_h_b = (const float*)d_in[15];
  const float* topic_c_w = (const float*)d_in[16];
  const float* topic_c_b = (const float*)d_in[17];
  const float* stop_p_w  = (const float*)d_in[18];
  const float* stop_p_b  = (const float*)d_in[19];
  const float* stop_c_w  = (const float*)d_in[20];
  const float* stop_c_b  = (const float*)d_in[21];
  const float* final_w   = (const float*)d_in[22];
  const float* final_b   = (const float*)d_in[23];

  uint8_t* wsp = (uint8_t*)d_ws;
  size_t off = 0;
  auto take = [&](size_t bytes) -> void* {
    void* p = wsp + off;
    off = (off + bytes + 255) & ~(size_t)255;
    return p;
  };

  short* encproj = (short*)take((size_t)B_ * NPOS * A_ * 2);   // 51.4 MB
  short* encw    = (short*)take((size_t)A_ * D_ * 2);
  short* w2cat   = (short*)take((size_t)NC * 1024 * 2);
  short* ctxwT   = (short*)take((size_t)D_ * 1024 * 2);
  short* Wc      = (short*)take((size_t)NC * D_ * 2);
  short* w13     = (short*)take((size_t)N13 * H_ * 2);
  float* biasc   = (float*)take((size_t)NC * 4);
  float* bias13  = (float*)take((size_t)N13 * 4);
  float* zeros   = (float*)take((size_t)D_ * 4);
  short* hbf     = (short*)take((size_t)B_ * H_ * 2);
  float* cst     = (float*)take((size_t)B_ * H_ * 4);
  float* gA      = (float*)take((size_t)B_ * N13 * 4);
  float* gB      = (float*)take((size_t)B_ * N13 * 4);
  float* g3      = (float*)take((size_t)B_ * NC * 4);
  short* attb    = (short*)take((size_t)B_ * D_ * 2);
  float* scbuf   = (float*)take((size_t)B_ * NPOS * 4);
  unsigned int* maxbuf = (unsigned int*)take(256);
  const size_t base0 = off;                                    // fallback chunk area
  const long   nv = (long)B_ * NPOS * D_;
  unsigned char* v8 = (unsigned char*)take((size_t)nv);        // 102.8 MB int8
  short* v16 = (short*)(wsp + off);
  const bool full = (ws_size >= off + (size_t)nv * 2);

  // ---- one-time weight prep ----
  {
    SegTab t;
    const float* srcs[8] = {enc_att_w, w_ih, topic_c_w, dec_att_w, w_hh,
                            stop_p_w, topic_h_w, stop_c_w};
    short* dsts[8] = {encw, w2cat, w2cat + (size_t)4096 * 1024,
                      w13 + (size_t)OFF_DEC * 1024, w13 + (size_t)OFF_WHH * 1024,
                      w13 + (size_t)OFF_STOPP * 1024, w13 + (size_t)OFF_TOPICH * 1024,
                      w13 + (size_t)OFF_STOPC * 1024};
    const int nel[8] = {1048576, 4194304, 1048576, 524288, 4194304, 262144, 1048576, 262144};
    int c = 0;
    for (int i = 0; i < 8; ++i) {
      t.src[i] = srcs[i]; t.dst[i] = dsts[i];
      t.cum[i] = c; c += nel[i] / 2048;
    }
    t.cum[8] = c;
    cvt_multi_k<<<c, 256, 0, stream>>>(t);
  }
  transpose_cvt_k<<<dim3(D_ / 32, 1024 / 32), 256, 0, stream>>>(ctx_w, ctxwT, 1024, D_);
  hipMemsetAsync(zeros, 0, (size_t)D_ * 4, stream);
  gemm_bt_k<1, 128, 0><<<dim3(D_ / 128, NC / 128), 256, 0, stream>>>(
      w2cat, ctxwT, zeros, Wc, NC, D_, 1024);
  biasc_k<<<NC / 4, 256, 0, stream>>>(w_ih, b_ih, topic_c_w, topic_c_b, ctx_b, biasc);
  biasinit_k<<<dim3(N13 / 256, B_ + 1), 256, 0, stream>>>(
      dec_att_b, b_hh, stop_p_b, topic_h_b, stop_c_b, bias13, gA);
  hipMemsetAsync(hbf, 0, (size_t)B_ * H_ * 2, stream);
  hipMemsetAsync(cst, 0, (size_t)B_ * H_ * 4, stream);
  hipMemsetAsync(maxbuf, 0, 4, stream);

  // ---- enc_proj = v @ enc_att_w^T + b ; v -> bf16 + int8 ----
  const int Mrows = B_ * NPOS;  // 50176 = 392*128
  if (full) {
    cvt_v_k<<<8192, 256, 0, stream>>>(vis, v16, maxbuf, nv);
    quant_v_k<<<8192, 256, 0, stream>>>(v16, v8, maxbuf, nv);
    gemm_bt_k<1, 128, 1><<<dim3(A_ / 128, Mrows / 128), 256, 0, stream>>>(
        v16, encw, enc_att_b, encproj, Mrows, A_, D_);
  } else {
    const size_t avail = (ws_size > base0) ? ws_size - base0 : 0;
    int dt = 1;
    const int cand[] = {56, 28, 14, 8, 7, 4, 2, 1};
    for (int c : cand)
      if ((392 % c) == 0 && (size_t)c * 128 * D_ * 2 <= avail) { dt = c; break; }
    short* vchunk = (short*)(wsp + base0);
    const int CR = dt * 128;
    for (int s = 0; s < Mrows; s += CR) {
      cvt_k<<<4096, 256, 0, stream>>>(vis + (size_t)s * D_, vchunk, (long)CR * D_);
      gemm_bt_k<1, 128, 0><<<dim3(A_ / 128, dt), 256, 0, stream>>>(
          vchunk, encw, enc_att_b, encproj + (size_t)s * A_, CR, A_, D_);
    }
  }

  // ---- sequential sentence-LSTM steps (6 kernels/step) ----
  float* gP = gA; float* gC = gB;
  for (int t = 0; t < T_; ++t) {
    scores_k<<<B_, 512, 0, stream>>>(encproj, gP, full_att_w, scbuf);
    if (full) pv_k<1><<<dim3(D_ / 512, B_), 256, 0, stream>>>(v8, scbuf, maxbuf, attb);
    else      pv_k<0><<<dim3(D_ / 512, B_), 256, 0, stream>>>(vis, scbuf, maxbuf, attb);
    gemm_bt_k<0, 32, 0><<<dim3(NC / 32, B_ / 128), 256, 0, stream>>>(
        attb, Wc, biasc, g3, B_, NC, D_);
    lstm_k<<<(B_ * H_) / 256, 256, 0, stream>>>(gP, g3, cst, hbf);
    gemm_bt_k<0, 32, 0><<<dim3(N13 / 32, B_ / 128), 256, 0, stream>>>(
        hbf, w13, bias13, gC, B_, N13, H_);
    final_k<<<B_, 256, 0, stream>>>(gP, gC, g3, final_w, final_b,
                                    (float*)d_out, (float*)d_out + (size_t)B_ * T_ * 1024, t);
    float* tmp = gP; gP = gC; gC = tmp;
  }
}

// Round 5
// 1169.658 us; speedup vs baseline: 2.3108x; 1.1711x over previous
//
#include <hip/hip_runtime.h>
#include <cstdint>

// ---- problem constants ----
#define B_   256
#define NPOS 196        // 14*14
#define D_   2048
#define H_   1024
#define A_   512
#define T_   10

// W13 = [dec_att_w(512); w_hh(4096); stop_p_w(256); topic_h_w(1024); stop_c_w(256)]
#define N13  6144
#define OFF_DEC    0
#define OFF_WHH    512
#define OFF_STOPP  4608
#define OFF_TOPICH 4864
#define OFF_STOPC  5888
// Wc = [w_ih(4096); topic_c_w(1024)] @ ctx_w   -> [5120 x 2048]
#define NC   5120

#define QMAX 6.5f
#define QSINV (127.f / QMAX)
#define QS    (QMAX / 127.f)

#define PS13 ((size_t)B_ * N13)
#define PSNC ((size_t)B_ * NC)

typedef __attribute__((ext_vector_type(8))) short bf16x8;
typedef __attribute__((ext_vector_type(4))) short bf16x4;
typedef __attribute__((ext_vector_type(4))) float f32x4;

__device__ __forceinline__ float b2f(short s) {
  union { unsigned int u; float f; } c;
  c.u = ((unsigned int)(unsigned short)s) << 16;
  return c.f;
}
__device__ __forceinline__ short f2b(float f) {
  union { float f; unsigned int u; } c; c.f = f;
  unsigned int u = c.u + 0x7fffu + ((c.u >> 16) & 1u);  // RNE
  return (short)(u >> 16);
}
__device__ __forceinline__ float fast_tanh(float x) {
  float a = fabsf(x);
  float e = __expf(-2.f * a);
  float t = __fdividef(1.f - e, 1.f + e);
  return x < 0.f ? -t : t;
}
__device__ __forceinline__ float fast_sigm(float x) {
  return __fdividef(1.f, 1.f + __expf(-x));
}

#define GLDS16(g, l) __builtin_amdgcn_global_load_lds( \
    (const __attribute__((address_space(1))) void*)(g), \
    (__attribute__((address_space(3))) void*)(l), 16, 0, 0)

// ---------------- fused: vis f32 -> v16 bf16 + v8 u8 (fixed scale) ----------------
__global__ __launch_bounds__(256) void cvtq_v_k(
    const float* __restrict__ in, short* __restrict__ v16,
    unsigned char* __restrict__ v8, long n)
{
  long i = ((long)blockIdx.x * blockDim.x + threadIdx.x) * 8;
  const long stride = (long)gridDim.x * blockDim.x * 8;
  for (; i < n; i += stride) {
    float4 a = *(const float4*)(in + i);
    float4 b = *(const float4*)(in + i + 4);
    bf16x8 o;
    o[0]=f2b(a.x); o[1]=f2b(a.y); o[2]=f2b(a.z); o[3]=f2b(a.w);
    o[4]=f2b(b.x); o[5]=f2b(b.y); o[6]=f2b(b.z); o[7]=f2b(b.w);
    *(bf16x8*)(v16 + i) = o;
    float v[8] = {a.x,a.y,a.z,a.w,b.x,b.y,b.z,b.w};
    unsigned int w0 = 0, w1 = 0;
    #pragma unroll
    for (int j = 0; j < 4; ++j) {
      float q = fminf(fmaxf(rintf(v[j] * QSINV), -127.f), 127.f) + 128.f;
      w0 |= ((unsigned int)(int)q) << (8 * j);
    }
    #pragma unroll
    for (int j = 0; j < 4; ++j) {
      float q = fminf(fmaxf(rintf(v[4+j] * QSINV), -127.f), 127.f) + 128.f;
      w1 |= ((unsigned int)(int)q) << (8 * j);
    }
    uint2 pk; pk.x = w0; pk.y = w1;
    *(uint2*)(v8 + i) = pk;
  }
}

// ---------------- plain fp32 -> bf16 (chunked fallback path) ----------------
__global__ void cvt_k(const float* __restrict__ in, short* __restrict__ out, long n)
{
  long i = ((long)blockIdx.x * blockDim.x + threadIdx.x) * 8;
  const long stride = (long)gridDim.x * blockDim.x * 8;
  for (; i < n; i += stride) {
    float4 a = *(const float4*)(in + i);
    float4 b = *(const float4*)(in + i + 4);
    bf16x8 o;
    o[0]=f2b(a.x); o[1]=f2b(a.y); o[2]=f2b(a.z); o[3]=f2b(a.w);
    o[4]=f2b(b.x); o[5]=f2b(b.y); o[6]=f2b(b.z); o[7]=f2b(b.w);
    *(bf16x8*)(out + i) = o;
  }
}

// ---------------- batched weight cvt: 8 segments ----------------
struct SegTab {
  const float* src[8];
  short* dst[8];
  int cum[9];
};
__global__ __launch_bounds__(256) void cvt_multi_k(SegTab t)
{
  int seg = 0;
  #pragma unroll
  for (int s = 0; s < 7; ++s) seg += (int)(blockIdx.x >= (unsigned)t.cum[s + 1]);
  const long i = ((long)(blockIdx.x - t.cum[seg]) * 256 + threadIdx.x) * 8;
  const float* in = t.src[seg];
  float4 a = *(const float4*)(in + i);
  float4 b = *(const float4*)(in + i + 4);
  bf16x8 o;
  o[0]=f2b(a.x); o[1]=f2b(a.y); o[2]=f2b(a.z); o[3]=f2b(a.w);
  o[4]=f2b(b.x); o[5]=f2b(b.y); o[6]=f2b(b.z); o[7]=f2b(b.w);
  *(bf16x8*)(t.dst[seg] + i) = o;
}

// ---------------- transpose + convert: in[R][C] f32 -> out[C][R] bf16 ----------------
__global__ __launch_bounds__(256) void transpose_cvt_k(
    const float* __restrict__ in, short* __restrict__ out, int R, int C)
{
  __shared__ float t[32][33];
  const int r0 = blockIdx.y * 32, c0 = blockIdx.x * 32;
  const int tx = threadIdx.x & 31, ty = threadIdx.x >> 5;
  #pragma unroll
  for (int i = 0; i < 32; i += 8)
    t[ty + i][tx] = in[(size_t)(r0 + ty + i) * C + c0 + tx];
  __syncthreads();
  #pragma unroll
  for (int i = 0; i < 32; i += 8)
    out[(size_t)(c0 + ty + i) * R + r0 + tx] = f2b(t[tx][ty + i]);
}

// ---------------- bias_c[r] = b[r] + dot(w2[r,:], ctx_b) ----------------
__global__ __launch_bounds__(256) void biasc_k(
    const float* __restrict__ w_ih, const float* __restrict__ b_ih,
    const float* __restrict__ topic_c_w, const float* __restrict__ topic_c_b,
    const float* __restrict__ ctx_b, float* __restrict__ out)
{
  const int r = blockIdx.x * 4 + (threadIdx.x >> 6);
  const int l = threadIdx.x & 63;
  const float* wr; float bb;
  if (r < 4096) { wr = w_ih + (size_t)r * 1024;               bb = b_ih[r]; }
  else          { wr = topic_c_w + (size_t)(r - 4096) * 1024; bb = topic_c_b[r - 4096]; }
  float s = 0.f;
  #pragma unroll
  for (int k = 0; k < 16; ++k) s += wr[l + 64 * k] * ctx_b[l + 64 * k];
  #pragma unroll
  for (int o = 32; o; o >>= 1) s += __shfl_down(s, o);
  if (!l) out[r] = s + bb;
}

// ---------------- assemble bias13 ----------------
__global__ __launch_bounds__(256) void bias13_k(
    const float* __restrict__ dec_att_b, const float* __restrict__ b_hh,
    const float* __restrict__ stop_p_b, const float* __restrict__ topic_h_b,
    const float* __restrict__ stop_c_b, float* __restrict__ bias13)
{
  const int j = blockIdx.x * 256 + threadIdx.x;
  float v;
  if      (j < OFF_WHH)    v = dec_att_b[j];
  else if (j < OFF_STOPP)  v = b_hh[j - OFF_WHH];
  else if (j < OFF_TOPICH) v = stop_p_b[j - OFF_STOPP];
  else if (j < OFF_STOPC)  v = topic_h_b[j - OFF_TOPICH];
  else                     v = stop_c_b[j - OFF_STOPC];
  bias13[j] = v;
}

// ---------------- bf16 MFMA GEMM: C = A[M,K] * B[N,K]^T (+ bias) ----------------
// KZ>1: grid.z = K-chunk; writes f32 partial (no bias) to Cout + z*M*N.
template<int OUTBF16, int BN, int SWZ, int KZ>
__global__ __launch_bounds__(256) void gemm_bt_k(
    const short* __restrict__ Aptr, const short* __restrict__ Bptr,
    const float* __restrict__ bias, void* __restrict__ Cout,
    int M, int N, int K)
{
  constexpr int TOT = 16 + BN / 8;
  constexpr int NW  = BN / 32;
  __shared__ short As[128 * 64];
  __shared__ short Bs[BN * 64];
  const int tid = threadIdx.x;
  const int l = tid & 63, wv = tid >> 6;
  const int wr = wv >> 1, wc = wv & 1;
  size_t m0, n0;
  if (SWZ) {  // grid (4, 392): A-panel blocks -> same XCD
    const int id  = blockIdx.y * 4 + blockIdx.x;
    const int xcd = id & 7, s = id >> 3;
    m0 = (size_t)(xcd * 49 + (s >> 2)) * 128;
    n0 = (size_t)(s & 3) * BN;
  } else {
    m0 = (size_t)blockIdx.y * 128;
    n0 = (size_t)blockIdx.x * BN;
  }
  const int srow = l >> 3, scol = (l & 7) * 8;
  const int lr = l & 15, lg = l >> 4;
  const int KC = K / KZ;
  const int kbase = (KZ > 1) ? blockIdx.z * KC : 0;

  f32x4 acc[4][NW];
  #pragma unroll
  for (int i = 0; i < 4; ++i)
    #pragma unroll
    for (int j = 0; j < NW; ++j) acc[i][j] = (f32x4){0.f, 0.f, 0.f, 0.f};

  for (int k0 = kbase; k0 < kbase + KC; k0 += 64) {
    #pragma unroll
    for (int i = 0; i < TOT / 4; ++i) {
      const int c = i * 4 + wv;
      if (c < 16) {
        const int row = c * 8 + srow;
        GLDS16(Aptr + (m0 + row) * (size_t)K + k0 + scol, As + c * 512);
      } else {
        const int row = (c - 16) * 8 + srow;
        GLDS16(Bptr + (n0 + row) * (size_t)K + k0 + scol, Bs + (c - 16) * 512);
      }
    }
    __syncthreads();
    #pragma unroll
    for (int kk = 0; kk < 64; kk += 32) {
      bf16x8 af[4], bfr[NW];
      #pragma unroll
      for (int m = 0; m < 4; ++m)
        af[m] = *(const bf16x8*)(As + (wr * 64 + m * 16 + lr) * 64 + kk + lg * 8);
      #pragma unroll
      for (int n = 0; n < NW; ++n)
        bfr[n] = *(const bf16x8*)(Bs + (wc * (BN / 2) + n * 16 + lr) * 64 + kk + lg * 8);
      #pragma unroll
      for (int m = 0; m < 4; ++m)
        #pragma unroll
        for (int n = 0; n < NW; ++n)
          acc[m][n] = __builtin_amdgcn_mfma_f32_16x16x32_bf16(af[m], bfr[n], acc[m][n], 0, 0, 0);
    }
    __syncthreads();
  }

  #pragma unroll
  for (int m = 0; m < 4; ++m) {
    const size_t row = m0 + wr * 64 + m * 16 + lg * 4;
    #pragma unroll
    for (int n = 0; n < NW; ++n) {
      const size_t col = n0 + wc * (BN / 2) + n * 16 + lr;
      if (KZ > 1) {
        float* Cp = (float*)Cout + (size_t)blockIdx.z * M * (size_t)N;
        #pragma unroll
        for (int r = 0; r < 4; ++r)
          Cp[(row + r) * (size_t)N + col] = acc[m][n][r];
      } else {
        const float bv = bias[col];
        #pragma unroll
        for (int r = 0; r < 4; ++r) {
          const float v = acc[m][n][r] + bv;
          if (OUTBF16) ((short*)Cout)[(row + r) * (size_t)N + col] = f2b(v);
          else         ((float*)Cout)[(row + r) * (size_t)N + col] = v;
        }
      }
    }
  }
}

// ---------------- fused final(t-1) + scores(t); one block (512 thr) per b ----------
// pcur = pair(t-1) partials (h_new(t-1)@W13), pprev = pair(t-2) partials.
template<int DO_FINAL, int DO_SCORES>
__global__ __launch_bounds__(512) void sf_k(
    const float* __restrict__ pcur, const float* __restrict__ pprev,
    const float* __restrict__ g3p, const float* __restrict__ biasc,
    const float* __restrict__ bias13,
    const short* __restrict__ encp, const float* __restrict__ fullw,
    const float* __restrict__ finw, const float* __restrict__ finb,
    float* __restrict__ scbuf, float* __restrict__ out_t,
    float* __restrict__ out_p, int tprev)
{
  const int b = blockIdx.x, tid = threadIdx.x;
  const int l = tid & 63, wv = tid >> 6;
  const size_t b13 = (size_t)b * N13;
  __shared__ float dec_s[A_], fw_s[A_], sc[NPOS], red[16], pp[256];

  if (DO_FINAL) {
    // topic(t-1) = tanh(h_new@topic_h_w + b + ctx@topic_c_w + b)
    float* ot = out_t + (size_t)b * (T_ * 1024) + (size_t)tprev * 1024;
    #pragma unroll
    for (int i = 0; i < 2; ++i) {
      const int j = tid + i * 512;
      float th = bias13[OFF_TOPICH + j] + pcur[b13 + OFF_TOPICH + j]
               + pcur[PS13 + b13 + OFF_TOPICH + j];
      float tc = biasc[4096 + j];
      #pragma unroll
      for (int z = 0; z < 4; ++z) tc += g3p[z * PSNC + (size_t)b * NC + 4096 + j];
      ot[j] = fast_tanh(th + tc);
    }
    if (tid < 256) {
      float a = bias13[OFF_STOPP + tid] + pprev[b13 + OFF_STOPP + tid]
              + pprev[PS13 + b13 + OFF_STOPP + tid];
      float c = bias13[OFF_STOPC + tid] + pcur[b13 + OFF_STOPC + tid]
              + pcur[PS13 + b13 + OFF_STOPC + tid];
      pp[tid] = fast_tanh(a + c);
    }
  }
  if (DO_SCORES && tid < A_) {
    dec_s[tid] = pcur[b13 + tid] + pcur[PS13 + b13 + tid] + bias13[tid];
    fw_s[tid]  = fullw[tid];
  }
  __syncthreads();

  if (DO_FINAL && wv < 2) {
    float s = 0.f;
    #pragma unroll
    for (int k = 0; k < 4; ++k) s += pp[l + 64 * k] * finw[wv * 256 + l + 64 * k];
    #pragma unroll
    for (int o = 32; o; o >>= 1) s += __shfl_down(s, o);
    if (!l) out_p[(size_t)b * (T_ * 2) + tprev * 2 + wv] = s + finb[wv];
  }

  if (DO_SCORES) {
    const short* ep = encp + (size_t)b * NPOS * A_;
    for (int n = wv; n < NPOS; n += 8) {
      bf16x8 e = *(const bf16x8*)(ep + (size_t)n * A_ + l * 8);
      float s = 0.f;
      #pragma unroll
      for (int j = 0; j < 8; ++j)
        s += fast_tanh(b2f(e[j]) + dec_s[l * 8 + j]) * fw_s[l * 8 + j];
      #pragma unroll
      for (int o = 32; o; o >>= 1) s += __shfl_down(s, o);
      if (!l) sc[n] = s;
    }
    __syncthreads();

    float lm = (tid < NPOS) ? sc[tid] : -3e38f;
    #pragma unroll
    for (int o = 32; o; o >>= 1) lm = fmaxf(lm, __shfl_down(lm, o));
    if (!l) red[wv] = lm;
    __syncthreads();
    float mx = red[0];
    #pragma unroll
    for (int i = 1; i < 8; ++i) mx = fmaxf(mx, red[i]);
    const float ev = (tid < NPOS) ? __expf(sc[tid] - mx) : 0.f;
    float es = ev;
    #pragma unroll
    for (int o = 32; o; o >>= 1) es += __shfl_down(es, o);
    if (!l) red[8 + wv] = es;
    __syncthreads();
    float tot = red[8];
    #pragma unroll
    for (int i = 1; i < 8; ++i) tot += red[8 + i];
    if (tid < NPOS) scbuf[(size_t)b * NPOS + tid] = ev * __fdividef(1.f, tot);
  }
}

// ---------------- PV: att_out = scores^T v ; grid (2, B) ----------------
template<int VMODE>   // 1: int8 ws, 0: fp32 vis
__global__ __launch_bounds__(256) void pv_k(
    const void* __restrict__ vptr, const float* __restrict__ scbuf,
    short* __restrict__ attout)
{
  const int b = blockIdx.y;
  const int dbase = blockIdx.x * 1024;
  const int tid = threadIdx.x;
  const int grp = tid >> 7;          // n parity
  const int dt = (tid & 127) * 8;
  __shared__ float sc[NPOS];
  __shared__ float tmp[1024];
  if (tid < NPOS) sc[tid] = scbuf[(size_t)b * NPOS + tid];
  __syncthreads();

  float a[8] = {0,0,0,0,0,0,0,0};
  if (VMODE == 1) {
    const unsigned char* vb = (const unsigned char*)vptr
        + (size_t)b * NPOS * D_ + dbase + dt;
    #pragma unroll 8
    for (int n = grp; n < NPOS; n += 2) {
      const float s = sc[n];
      const uint2 w = *(const uint2*)(vb + (size_t)n * D_);
      a[0] += s * (float)(w.x & 255u);
      a[1] += s * (float)((w.x >> 8) & 255u);
      a[2] += s * (float)((w.x >> 16) & 255u);
      a[3] += s * (float)(w.x >> 24);
      a[4] += s * (float)(w.y & 255u);
      a[5] += s * (float)((w.y >> 8) & 255u);
      a[6] += s * (float)((w.y >> 16) & 255u);
      a[7] += s * (float)(w.y >> 24);
    }
  } else {
    const float* vf = (const float*)vptr + (size_t)b * NPOS * D_ + dbase + dt;
    #pragma unroll 2
    for (int n = grp; n < NPOS; n += 2) {
      const float s = sc[n];
      float4 v0 = *(const float4*)(vf + (size_t)n * D_);
      float4 v1 = *(const float4*)(vf + (size_t)n * D_ + 4);
      a[0] += s*v0.x; a[1] += s*v0.y; a[2] += s*v0.z; a[3] += s*v0.w;
      a[4] += s*v1.x; a[5] += s*v1.y; a[6] += s*v1.z; a[7] += s*v1.w;
    }
  }
  if (grp == 1) {
    #pragma unroll
    for (int j = 0; j < 8; ++j) tmp[dt + j] = a[j];
  }
  __syncthreads();
  if (grp == 0) {
    bf16x8 o8;
    #pragma unroll
    for (int j = 0; j < 8; ++j) {
      float v = a[j] + tmp[dt + j];
      if (VMODE == 1) v = v * QS - 128.f * QS;   // sum(sc)=1
      o8[j] = f2b(v);
    }
    *(bf16x8*)(attout + (size_t)b * D_ + dbase + dt) = o8;
  }
}

// ---------------- LSTM cell: sums split-K partials + biases ----------------
__global__ __launch_bounds__(256) void lstm_k(
    const float* __restrict__ g3p, const float* __restrict__ gPp,
    const float* __restrict__ biasc, const float* __restrict__ bias13,
    float* __restrict__ c, short* __restrict__ hbf)
{
  const int idx = (blockIdx.x * 256 + threadIdx.x) * 4;  // 0..B*H-1 step 4
  const int b = idx >> 10, j = idx & 1023;
  f32x4 gate[4];
  #pragma unroll
  for (int g = 0; g < 4; ++g) {
    const size_t base  = (size_t)b * NC + g * 1024 + j;
    const size_t baseh = (size_t)b * N13 + OFF_WHH + g * 1024 + j;
    f32x4 s = *(const f32x4*)(biasc + g * 1024 + j);
    s += *(const f32x4*)(bias13 + OFF_WHH + g * 1024 + j);
    #pragma unroll
    for (int z = 0; z < 4; ++z) s += *(const f32x4*)(g3p + z * PSNC + base);
    #pragma unroll
    for (int z = 0; z < 2; ++z) s += *(const f32x4*)(gPp + z * PS13 + baseh);
    gate[g] = s;
  }
  f32x4 cv = *(const f32x4*)(c + idx);
  f32x4 cn;
  bf16x4 hn;
  #pragma unroll
  for (int k = 0; k < 4; ++k) {
    const float nc2 = fast_sigm(gate[1][k]) * cv[k]
                    + fast_sigm(gate[0][k]) * fast_tanh(gate[2][k]);
    cn[k] = nc2;
    hn[k] = f2b(fast_sigm(gate[3][k]) * fast_tanh(nc2));
  }
  *(f32x4*)(c + idx) = cn;
  *(bf16x4*)(hbf + idx) = hn;
}

// ---------------- host ----------------
extern "C" void kernel_launch(void* const* d_in, const int* in_sizes, int n_in,
                              void* d_out, int out_size, void* d_ws, size_t ws_size,
                              hipStream_t stream)
{
  const float* vis       = (const float*)d_in[0];
  const float* enc_att_w = (const float*)d_in[2];
  const float* enc_att_b = (const float*)d_in[3];
  const float* dec_att_w = (const float*)d_in[4];
  const float* dec_att_b = (const float*)d_in[5];
  const float* full_att_w= (const float*)d_in[6];
  const float* ctx_w     = (const float*)d_in[8];
  const float* ctx_b     = (const float*)d_in[9];
  const float* w_ih      = (const float*)d_in[10];
  const float* b_ih      = (const float*)d_in[11];
  const float* w_hh      = (const float*)d_in[12];
  const float* b_hh      = (const float*)d_in[13];
  const float* topic_h_w = (const float*)d_in[14];
  const float* topic_h_b = (const float*)d_in[15];
  const float* topic_c_w = (const float*)d_in[16];
  const float* topic_c_b = (const float*)d_in[17];
  const float* stop_p_w  = (const float*)d_in[18];
  const float* stop_p_b  = (const float*)d_in[19];
  const float* stop_c_w  = (const float*)d_in[20];
  const float* stop_c_b  = (const float*)d_in[21];
  const float* final_w   = (const float*)d_in[22];
  const float* final_b   = (const float*)d_in[23];

  uint8_t* wsp = (uint8_t*)d_ws;
  size_t off = 0;
  auto take = [&](size_t bytes) -> void* {
    void* p = wsp + off;
    off = (off + bytes + 255) & ~(size_t)255;
    return p;
  };

  short* encproj = (short*)take((size_t)B_ * NPOS * A_ * 2);   // 51.4 MB
  short* encw    = (short*)take((size_t)A_ * D_ * 2);
  short* w2cat   = (short*)take((size_t)NC * 1024 * 2);
  short* ctxwT   = (short*)take((size_t)D_ * 1024 * 2);
  short* Wc      = (short*)take((size_t)NC * D_ * 2);
  short* w13     = (short*)take((size_t)N13 * H_ * 2);
  float* biasc   = (float*)take((size_t)NC * 4);
  float* bias13  = (float*)take((size_t)N13 * 4);
  float* zeros   = (float*)take((size_t)D_ * 4);
  short* hbf     = (short*)take((size_t)B_ * H_ * 2);
  float* cst     = (float*)take((size_t)B_ * H_ * 4);
  float* pairs0  = (float*)take(2 * PS13 * 4);    // 12.6 MB (2 partials)
  float* pairs1  = (float*)take(2 * PS13 * 4);
  float* g3p     = (float*)take(4 * PSNC * 4);    // 21 MB (4 partials)
  short* attb    = (short*)take((size_t)B_ * D_ * 2);
  float* scbuf   = (float*)take((size_t)B_ * NPOS * 4);
  const size_t base0 = off;                                    // fallback chunk area
  const long   nv = (long)B_ * NPOS * D_;
  unsigned char* v8 = (unsigned char*)take((size_t)nv);        // 102.8 MB int8
  short* v16 = (short*)(wsp + off);
  const bool full = (ws_size >= off + (size_t)nv * 2);

  float* out_t = (float*)d_out;
  float* out_p = (float*)d_out + (size_t)B_ * T_ * 1024;

  // ---- one-time weight prep ----
  {
    SegTab t;
    const float* srcs[8] = {enc_att_w, w_ih, topic_c_w, dec_att_w, w_hh,
                            stop_p_w, topic_h_w, stop_c_w};
    short* dsts[8] = {encw, w2cat, w2cat + (size_t)4096 * 1024,
                      w13 + (size_t)OFF_DEC * 1024, w13 + (size_t)OFF_WHH * 1024,
                      w13 + (size_t)OFF_STOPP * 1024, w13 + (size_t)OFF_TOPICH * 1024,
                      w13 + (size_t)OFF_STOPC * 1024};
    const int nel[8] = {1048576, 4194304, 1048576, 524288, 4194304, 262144, 1048576, 262144};
    int c = 0;
    for (int i = 0; i < 8; ++i) {
      t.src[i] = srcs[i]; t.dst[i] = dsts[i];
      t.cum[i] = c; c += nel[i] / 2048;
    }
    t.cum[8] = c;
    cvt_multi_k<<<c, 256, 0, stream>>>(t);
  }
  transpose_cvt_k<<<dim3(D_ / 32, 1024 / 32), 256, 0, stream>>>(ctx_w, ctxwT, 1024, D_);
  hipMemsetAsync(zeros, 0, (size_t)D_ * 4, stream);
  gemm_bt_k<1, 128, 0, 1><<<dim3(D_ / 128, NC / 128), 256, 0, stream>>>(
      w2cat, ctxwT, zeros, Wc, NC, D_, 1024);
  biasc_k<<<NC / 4, 256, 0, stream>>>(w_ih, b_ih, topic_c_w, topic_c_b, ctx_b, biasc);
  bias13_k<<<N13 / 256, 256, 0, stream>>>(
      dec_att_b, b_hh, stop_p_b, topic_h_b, stop_c_b, bias13);
  hipMemsetAsync(cst, 0, (size_t)B_ * H_ * 4, stream);
  hipMemsetAsync(pairs1, 0, 2 * PS13 * 4, stream);   // pair(-1) = 0 (h0 = 0)

  // ---- enc_proj = v @ enc_att_w^T + b ; v -> bf16 + int8 ----
  const int Mrows = B_ * NPOS;  // 50176 = 392*128
  if (full) {
    cvtq_v_k<<<8192, 256, 0, stream>>>(vis, v16, v8, nv);
    gemm_bt_k<1, 128, 1, 1><<<dim3(A_ / 128, Mrows / 128), 256, 0, stream>>>(
        v16, encw, enc_att_b, encproj, Mrows, A_, D_);
  } else {
    const size_t avail = (ws_size > base0) ? ws_size - base0 : 0;
    int dt = 1;
    const int cand[] = {56, 28, 14, 8, 7, 4, 2, 1};
    for (int c : cand)
      if ((392 % c) == 0 && (size_t)c * 128 * D_ * 2 <= avail) { dt = c; break; }
    short* vchunk = (short*)(wsp + base0);
    const int CR = dt * 128;
    for (int s = 0; s < Mrows; s += CR) {
      cvt_k<<<4096, 256, 0, stream>>>(vis + (size_t)s * D_, vchunk, (long)CR * D_);
      gemm_bt_k<1, 128, 0, 1><<<dim3(A_ / 128, dt), 256, 0, stream>>>(
          vchunk, encw, enc_att_b, encproj + (size_t)s * A_, CR, A_, D_);
    }
  }

  // ---- sequential sentence-LSTM steps (5 kernels/step) ----
  // pair(t) = (t&1) ? pairs1 : pairs0 ; pair(-1) = pairs1 (zeroed)
  for (int t = 0; t < T_; ++t) {
    float* pcur  = (t & 1) ? pairs0 : pairs1;   // pair(t-1)
    float* pprev = (t & 1) ? pairs1 : pairs0;   // pair(t-2)
    if (t == 0)
      sf_k<0, 1><<<B_, 512, 0, stream>>>(pcur, pprev, g3p, biasc, bias13,
          encproj, full_att_w, final_w, final_b, scbuf, out_t, out_p, 0);
    else
      sf_k<1, 1><<<B_, 512, 0, stream>>>(pcur, pprev, g3p, biasc, bias13,
          encproj, full_att_w, final_w, final_b, scbuf, out_t, out_p, t - 1);
    if (full) pv_k<1><<<dim3(2, B_), 256, 0, stream>>>(v8, scbuf, attb);
    else      pv_k<0><<<dim3(2, B_), 256, 0, stream>>>(vis, scbuf, attb);
    // g3 partials: att_out @ Wc^T, split-K 4
    gemm_bt_k<0, 32, 0, 4><<<dim3(NC / 32, B_ / 128, 4), 256, 0, stream>>>(
        attb, Wc, nullptr, g3p, B_, NC, D_);
    lstm_k<<<(B_ * H_) / 1024, 256, 0, stream>>>(g3p, pcur, biasc, bias13, cst, hbf);
    // pair(t) partials: h_new @ W13^T, split-K 2
    float* pnew = (t & 1) ? pairs1 : pairs0;
    gemm_bt_k<0, 32, 0, 2><<<dim3(N13 / 32, B_ / 128, 2), 256, 0, stream>>>(
        hbf, w13, nullptr, pnew, B_, N13, H_);
  }
  // tail: final(T-1)
  {
    float* pcur  = ((T_ - 1) & 1) ? pairs1 : pairs0;  // pair(9)
    float* pprev = ((T_ - 1) & 1) ? pairs0 : pairs1;  // pair(8)
    sf_k<1, 0><<<B_, 512, 0, stream>>>(pcur, pprev, g3p, biasc, bias13,
        encproj, full_att_w, final_w, final_b, scbuf, out_t, out_p, T_ - 1);
  }
}